// Round 1
// baseline (3691.592 us; speedup 1.0000x reference)
//
#include <hip/hip_runtime.h>
#include <math.h>

// sLSTM cell: B=16384, D=H=1024.
// Kernel 1 (gates): pre_g = x@Wg + h_prev@Rg + (bWg+bRg+bg) for g in {z,i,f,o},
//   fused epilogue -> h, C, n written straight to d_out (no workspace).
// Kernel 2: y = h @ Wy + by, reading h from d_out.
// d_out layout (return order): y[B*D], h[B*H], C[B*H], n[B*H], all f32.

constexpr int Bsz = 16384;
constexpr int Dd  = 1024;
constexpr int Hh  = 1024;
constexpr float EPSv = 1e-7f;

constexpr int BM = 64, BN = 64, BK = 16;
constexpr int PAD = 4;   // keeps 16B alignment of float4 rows, breaks power-of-2 stride

__global__ __launch_bounds__(256)
void gates_kernel(const float* __restrict__ x, const float* __restrict__ h_prev,
                  const float* __restrict__ c_prev, const float* __restrict__ n_prev,
                  const float* __restrict__ Wz, const float* __restrict__ Rz,
                  const float* __restrict__ Wi, const float* __restrict__ Ri,
                  const float* __restrict__ Wf, const float* __restrict__ Rf,
                  const float* __restrict__ Wo, const float* __restrict__ Ro,
                  const float* __restrict__ bWz, const float* __restrict__ bRz, const float* __restrict__ bz,
                  const float* __restrict__ bWi, const float* __restrict__ bRi, const float* __restrict__ bi,
                  const float* __restrict__ bWf, const float* __restrict__ bRf, const float* __restrict__ bf_,
                  const float* __restrict__ bWo, const float* __restrict__ bRo, const float* __restrict__ bo,
                  float* __restrict__ out_h, float* __restrict__ out_C, float* __restrict__ out_n)
{
    __shared__ float sA[BK][BM + PAD];        // A tile, k-major (transposed on load)
    __shared__ float sB[4][BK][BN + PAD];     // one weight tile per gate

    const int t = threadIdx.x;
    const int col_blk = blockIdx.x & 15;      // 16 column blocks (H/BN)
    const int row_blk = blockIdx.x >> 4;      // 256 row blocks (B/BM)
    const int row0 = row_blk * BM;
    const int col0 = col_blk * BN;

    const int tx = t & 15;                    // 16 col groups
    const int ty = t >> 4;                    // 16 row groups

    float acc[4][4][4];
    #pragma unroll
    for (int g = 0; g < 4; ++g)
        #pragma unroll
        for (int i = 0; i < 4; ++i)
            #pragma unroll
            for (int j = 0; j < 4; ++j) acc[g][i][j] = 0.f;

    // staging index maps
    const int ar = t >> 2;            // 0..63 : A row within tile
    const int ak = (t & 3) * 4;       // 0,4,8,12 : A k-offset (float4)
    const int wk = t >> 4;            // 0..15 : W k-row
    const int wc = (t & 15) * 4;      // 0..60 : W col offset (float4)

    for (int phase = 0; phase < 2; ++phase) {
        const float* A  = phase ? h_prev : x;
        const float* W0 = phase ? Rz : Wz;
        const float* W1 = phase ? Ri : Wi;
        const float* W2 = phase ? Rf : Wf;
        const float* W3 = phase ? Ro : Wo;
        for (int k0 = 0; k0 < 1024; k0 += BK) {
            __syncthreads();   // protect LDS from previous iteration's readers
            {
                const float4 v = *(const float4*)(A + (size_t)(row0 + ar) * 1024 + k0 + ak);
                sA[ak + 0][ar] = v.x;
                sA[ak + 1][ar] = v.y;
                sA[ak + 2][ar] = v.z;
                sA[ak + 3][ar] = v.w;
            }
            *(float4*)&sB[0][wk][wc] = *(const float4*)(W0 + (size_t)(k0 + wk) * 1024 + col0 + wc);
            *(float4*)&sB[1][wk][wc] = *(const float4*)(W1 + (size_t)(k0 + wk) * 1024 + col0 + wc);
            *(float4*)&sB[2][wk][wc] = *(const float4*)(W2 + (size_t)(k0 + wk) * 1024 + col0 + wc);
            *(float4*)&sB[3][wk][wc] = *(const float4*)(W3 + (size_t)(k0 + wk) * 1024 + col0 + wc);
            __syncthreads();
            #pragma unroll
            for (int kk = 0; kk < BK; ++kk) {
                float a[4], bb[4][4];
                *(float4*)a        = *(const float4*)&sA[kk][ty * 4];
                *(float4*)&bb[0][0] = *(const float4*)&sB[0][kk][tx * 4];
                *(float4*)&bb[1][0] = *(const float4*)&sB[1][kk][tx * 4];
                *(float4*)&bb[2][0] = *(const float4*)&sB[2][kk][tx * 4];
                *(float4*)&bb[3][0] = *(const float4*)&sB[3][kk][tx * 4];
                #pragma unroll
                for (int g = 0; g < 4; ++g)
                    #pragma unroll
                    for (int i = 0; i < 4; ++i)
                        #pragma unroll
                        for (int j = 0; j < 4; ++j)
                            acc[g][i][j] += a[i] * bb[g][j];
            }
        }
    }

    // epilogue: biases + activations + state update
    #pragma unroll
    for (int i = 0; i < 4; ++i) {
        const int r = row0 + ty * 4 + i;
        #pragma unroll
        for (int j = 0; j < 4; ++j) {
            const int c = col0 + tx * 4 + j;
            const float pz = acc[0][i][j] + bWz[c] + bRz[c] + bz[c];
            const float pi = acc[1][i][j] + bWi[c] + bRi[c] + bi[c];
            const float pf = acc[2][i][j] + bWf[c] + bRf[c] + bf_[c];
            const float po = acc[3][i][j] + bWo[c] + bRo[c] + bo[c];
            const float zt = tanhf(pz);
            const float it = expf(pi);
            const float ft = 1.f / (1.f + expf(-pf));
            const float ot = 1.f / (1.f + expf(-po));
            const size_t idx = (size_t)r * Hh + c;
            const float Cv = ft * c_prev[idx] + it * zt;
            const float nv = ft * n_prev[idx] + it;
            const float hv = ot * tanhf(Cv / (nv + EPSv));
            out_h[idx] = hv;
            out_C[idx] = Cv;
            out_n[idx] = nv;
        }
    }
}

__global__ __launch_bounds__(256)
void ygemm_kernel(const float* __restrict__ hmat, const float* __restrict__ Wy,
                  const float* __restrict__ by, float* __restrict__ y)
{
    __shared__ float sA[BK][BM + PAD];
    __shared__ float sB[BK][BN + PAD];

    const int t = threadIdx.x;
    const int col_blk = blockIdx.x & 15;
    const int row_blk = blockIdx.x >> 4;
    const int row0 = row_blk * BM;
    const int col0 = col_blk * BN;

    const int tx = t & 15;
    const int ty = t >> 4;

    float acc[4][4];
    #pragma unroll
    for (int i = 0; i < 4; ++i)
        #pragma unroll
        for (int j = 0; j < 4; ++j) acc[i][j] = 0.f;

    const int ar = t >> 2;
    const int ak = (t & 3) * 4;
    const int wk = t >> 4;
    const int wc = (t & 15) * 4;

    for (int k0 = 0; k0 < 1024; k0 += BK) {
        __syncthreads();
        {
            const float4 v = *(const float4*)(hmat + (size_t)(row0 + ar) * 1024 + k0 + ak);
            sA[ak + 0][ar] = v.x;
            sA[ak + 1][ar] = v.y;
            sA[ak + 2][ar] = v.z;
            sA[ak + 3][ar] = v.w;
        }
        *(float4*)&sB[wk][wc] = *(const float4*)(Wy + (size_t)(k0 + wk) * 1024 + col0 + wc);
        __syncthreads();
        #pragma unroll
        for (int kk = 0; kk < BK; ++kk) {
            float a[4], bb[4];
            *(float4*)a  = *(const float4*)&sA[kk][ty * 4];
            *(float4*)bb = *(const float4*)&sB[kk][tx * 4];
            #pragma unroll
            for (int i = 0; i < 4; ++i)
                #pragma unroll
                for (int j = 0; j < 4; ++j)
                    acc[i][j] += a[i] * bb[j];
        }
    }

    #pragma unroll
    for (int i = 0; i < 4; ++i) {
        const int r = row0 + ty * 4 + i;
        #pragma unroll
        for (int j = 0; j < 4; ++j) {
            const int c = col0 + tx * 4 + j;
            y[(size_t)r * Dd + c] = acc[i][j] + by[c];
        }
    }
}

extern "C" void kernel_launch(void* const* d_in, const int* in_sizes, int n_in,
                              void* d_out, int out_size, void* d_ws, size_t ws_size,
                              hipStream_t stream) {
    const float* x      = (const float*)d_in[0];
    const float* h_prev = (const float*)d_in[1];
    const float* c_prev = (const float*)d_in[2];
    const float* n_prev = (const float*)d_in[3];
    const float* Wz  = (const float*)d_in[4];
    const float* bWz = (const float*)d_in[5];
    const float* Rz  = (const float*)d_in[6];
    const float* bRz = (const float*)d_in[7];
    const float* bz  = (const float*)d_in[8];
    const float* Wi  = (const float*)d_in[9];
    const float* bWi = (const float*)d_in[10];
    const float* Ri  = (const float*)d_in[11];
    const float* bRi = (const float*)d_in[12];
    const float* bi  = (const float*)d_in[13];
    const float* Wf  = (const float*)d_in[14];
    const float* bWf = (const float*)d_in[15];
    const float* Rf  = (const float*)d_in[16];
    const float* bRf = (const float*)d_in[17];
    const float* bf_ = (const float*)d_in[18];
    const float* Wo  = (const float*)d_in[19];
    const float* bWo = (const float*)d_in[20];
    const float* Ro  = (const float*)d_in[21];
    const float* bRo = (const float*)d_in[22];
    const float* bo  = (const float*)d_in[23];
    const float* Wy  = (const float*)d_in[24];
    const float* by  = (const float*)d_in[25];

    float* y     = (float*)d_out;
    float* out_h = y + (size_t)Bsz * Dd;
    float* out_C = out_h + (size_t)Bsz * Hh;
    float* out_n = out_C + (size_t)Bsz * Hh;

    dim3 block(256);
    dim3 grid((Bsz / BM) * (Hh / BN));   // 4096 blocks

    gates_kernel<<<grid, block, 0, stream>>>(x, h_prev, c_prev, n_prev,
                                             Wz, Rz, Wi, Ri, Wf, Rf, Wo, Ro,
                                             bWz, bRz, bz, bWi, bRi, bi,
                                             bWf, bRf, bf_, bWo, bRo, bo,
                                             out_h, out_C, out_n);
    ygemm_kernel<<<grid, block, 0, stream>>>(out_h, Wy, by, y);
}

// Round 2
// 578.377 us; speedup vs baseline: 6.3827x; 6.3827x over previous
//
#include <hip/hip_runtime.h>
#include <math.h>
#include <stdint.h>

// sLSTM cell, B=16384, D=H=1024.
// bf16-MFMA path (needs ws >= ~114 MB):
//   cvt kernels build: A=[x|h_prev] bf16 [16384][2048], WT gate-interleaved bf16 [4096][2048],
//   WyT bf16 [1024][1024], bsum f32 [4][1024].
//   gemm_gates: m97-style 128x128 MFMA GEMM, fused gate epilogue -> h,C,n (f32) + h_bf.
//   gemm_y: same GEMM core, y = h @ Wy + by.
// Fallback (small ws): round-1 f32 vector kernels.

typedef __attribute__((ext_vector_type(8))) short bf16x8;
typedef __attribute__((ext_vector_type(4))) float f32x4;

constexpr int Bsz = 16384;
constexpr int Dd  = 1024;
constexpr int Hh  = 1024;
constexpr float EPSv = 1e-7f;

__device__ __forceinline__ unsigned short f2bf(float f) {
    union { float f; uint32_t u; } v; v.f = f;
    uint32_t u = v.u + 0x7fffu + ((v.u >> 16) & 1u);   // RNE
    return (unsigned short)(u >> 16);
}

__device__ __forceinline__ void gload16(const void* g, void* l) {
    __builtin_amdgcn_global_load_lds(
        (const __attribute__((address_space(1))) void*)g,
        (__attribute__((address_space(3))) void*)l, 16, 0, 0);
}

// ---------------- conversion kernels ----------------

__global__ __launch_bounds__(256)
void cvt_A(const float* __restrict__ x, const float* __restrict__ hp, unsigned short* __restrict__ A)
{
    const int idx = blockIdx.x * 256 + threadIdx.x;   // 8 elements each
    const int n = idx * 8;
    const int b = n >> 11, k = n & 2047;
    const float* s = (k < 1024) ? (x + (size_t)b * 1024 + k)
                                : (hp + (size_t)b * 1024 + (k - 1024));
    const float4 v0 = *(const float4*)s;
    const float4 v1 = *(const float4*)(s + 4);
    union { unsigned short u[8]; uint4 v; } pk;
    pk.u[0] = f2bf(v0.x); pk.u[1] = f2bf(v0.y); pk.u[2] = f2bf(v0.z); pk.u[3] = f2bf(v0.w);
    pk.u[4] = f2bf(v1.x); pk.u[5] = f2bf(v1.y); pk.u[6] = f2bf(v1.z); pk.u[7] = f2bf(v1.w);
    *(uint4*)(A + n) = pk.v;
}

// src [1024][1024] f32 (rows=k, cols=j) -> dst[c'][kbase+k] bf16.
// mode 0: c' = (j&15)|(g<<4)|((j>>4)<<6)   (gate-interleaved)
// mode 1: c' = j
__global__ __launch_bounds__(256)
void cvt_T(const float* __restrict__ src, unsigned short* __restrict__ dst,
           int ldd, int kbase, int g, int mode)
{
    __shared__ float tile[64][65];
    const int t = threadIdx.x;
    const int kt = blockIdx.x & 15, jt = blockIdx.x >> 4;
    {
        const int lr = t >> 4, lc = (t & 15) * 4;
        #pragma unroll
        for (int rr = 0; rr < 64; rr += 16) {
            const float4 v = *(const float4*)(src + (size_t)(kt * 64 + rr + lr) * 1024 + jt * 64 + lc);
            tile[rr + lr][lc + 0] = v.x;
            tile[rr + lr][lc + 1] = v.y;
            tile[rr + lr][lc + 2] = v.z;
            tile[rr + lr][lc + 3] = v.w;
        }
    }
    __syncthreads();
    const int jl = t >> 2, kc = (t & 3) * 16;
    const int j = jt * 64 + jl;
    const int cp = mode ? j : ((j & 15) | (g << 4) | ((j >> 4) << 6));
    union { unsigned short u[16]; uint4 v[2]; } pk;
    #pragma unroll
    for (int q = 0; q < 16; ++q) pk.u[q] = f2bf(tile[kc + q][jl]);
    uint4* d = (uint4*)(dst + (size_t)cp * ldd + kbase + kt * 64 + kc);
    d[0] = pk.v[0];
    d[1] = pk.v[1];
}

__global__ __launch_bounds__(256)
void bias_sum(const float* bWz, const float* bRz, const float* bz,
              const float* bWi, const float* bRi, const float* bi,
              const float* bWf, const float* bRf, const float* bf_,
              const float* bWo, const float* bRo, const float* bo,
              float* __restrict__ bs)
{
    const int j = blockIdx.x * 256 + threadIdx.x;   // grid 4
    bs[j]        = bWz[j] + bRz[j] + bz[j];
    bs[1024 + j] = bWi[j] + bRi[j] + bi[j];
    bs[2048 + j] = bWf[j] + bRf[j] + bf_[j];
    bs[3072 + j] = bWo[j] + bRo[j] + bo[j];
}

// ---------------- MFMA GEMM core (m97 structure) ----------------
// 128x128 tile, BK=32, 256 threads = 4 waves (2x2 of 64x64), single-buffered LDS,
// global_load_lds width 16, bf16x8 ds reads, mfma_f32_16x16x32_bf16.

__device__ __forceinline__ void mfma_loop(const unsigned short* __restrict__ Ag, int ldA,
                                          const unsigned short* __restrict__ Bg, int ldB,
                                          int K, int m0, int n0, int t,
                                          unsigned short* sA, unsigned short* sB,
                                          f32x4 acc[4][4])
{
    const int lane = t & 63;
    const int wid  = t >> 6;
    const int wr = wid >> 1, wc = wid & 1;
    const int cl = lane & 15, hi = lane >> 4;

    const int o1 = t * 16, o2 = o1 + 4096;       // LDS byte offsets (tile = 8192 B)
    const int r1 = t >> 2, r2 = r1 + 64;         // tile row staged by this thread
    const int kb = (t & 3) * 16;                 // byte offset within 64-B k-row

    const char* pA1 = (const char*)(Ag + (size_t)(m0 + r1) * ldA) + kb;
    const char* pA2 = (const char*)(Ag + (size_t)(m0 + r2) * ldA) + kb;
    const char* pB1 = (const char*)(Bg + (size_t)(n0 + r1) * ldB) + kb;
    const char* pB2 = (const char*)(Bg + (size_t)(n0 + r2) * ldB) + kb;
    char* lA1 = (char*)sA + o1; char* lA2 = (char*)sA + o2;
    char* lB1 = (char*)sB + o1; char* lB2 = (char*)sB + o2;

    for (int k0 = 0; k0 < K; k0 += 32) {
        const size_t kby = (size_t)k0 * 2;
        __syncthreads();                          // prev iter's LDS reads done
        gload16(pA1 + kby, lA1);
        gload16(pA2 + kby, lA2);
        gload16(pB1 + kby, lB1);
        gload16(pB2 + kby, lB2);
        __syncthreads();                          // staging complete (vmcnt drained)
        bf16x8 av[4], bv[4];
        #pragma unroll
        for (int i = 0; i < 4; ++i)
            av[i] = *(const bf16x8*)(sA + ((wr * 64 + i * 16 + cl) << 5) + (hi << 3));
        #pragma unroll
        for (int j = 0; j < 4; ++j)
            bv[j] = *(const bf16x8*)(sB + ((wc * 64 + j * 16 + cl) << 5) + (hi << 3));
        #pragma unroll
        for (int i = 0; i < 4; ++i)
            #pragma unroll
            for (int j = 0; j < 4; ++j)
                acc[i][j] = __builtin_amdgcn_mfma_f32_16x16x32_bf16(av[i], bv[j], acc[i][j], 0, 0, 0);
    }
}

// gates GEMM: A [16384][2048] bf16, WT [4096][2048] bf16 (gate-interleaved cols).
__global__ __launch_bounds__(256)
void gemm_gates(const unsigned short* __restrict__ A, const unsigned short* __restrict__ WT,
                const float* __restrict__ bsum,
                const float* __restrict__ c_prev, const float* __restrict__ n_prev,
                float* __restrict__ out_h, float* __restrict__ out_C, float* __restrict__ out_n,
                unsigned short* __restrict__ h_bf)
{
    __shared__ unsigned short sA[128 * 32], sB[128 * 32];
    const int t = threadIdx.x;
    // 4096 blocks = 128 row-blocks x 32 col-blocks; XCD-aware swizzle (4096 % 8 == 0)
    const int swz = (blockIdx.x & 7) * 512 + (blockIdx.x >> 3);
    const int mblk = swz & 127, nblk = swz >> 7;
    const int m0 = mblk * 128, n0 = nblk * 128;

    f32x4 acc[4][4];
    #pragma unroll
    for (int i = 0; i < 4; ++i)
        #pragma unroll
        for (int j = 0; j < 4; ++j) acc[i][j] = (f32x4)0.f;

    mfma_loop(A, 2048, WT, 2048, 2048, m0, n0, t, sA, sB, acc);

    // epilogue: lane-local gate combine.
    const int lane = t & 63, wid = t >> 6;
    const int wr = wid >> 1, wc = wid & 1;
    const int cl = lane & 15, hi = lane >> 4;
    const int j = nblk * 32 + wc * 16 + cl;       // output column 0..1023
    const float bz_ = bsum[j];
    const float bi_ = bsum[1024 + j];
    const float bf_ = bsum[2048 + j];
    const float bo_ = bsum[3072 + j];
    #pragma unroll
    for (int i = 0; i < 4; ++i) {
        const int rb = m0 + wr * 64 + i * 16 + hi * 4;
        #pragma unroll
        for (int r = 0; r < 4; ++r) {
            const size_t idx = (size_t)(rb + r) * 1024 + j;
            const float pz = acc[i][0][r] + bz_;
            const float pi = acc[i][1][r] + bi_;
            const float pf = acc[i][2][r] + bf_;
            const float po = acc[i][3][r] + bo_;
            const float zt = tanhf(pz);
            const float it = expf(pi);
            const float ft = 1.f / (1.f + expf(-pf));
            const float ot = 1.f / (1.f + expf(-po));
            const float Cv = ft * c_prev[idx] + it * zt;
            const float nv = ft * n_prev[idx] + it;
            const float hv = ot * tanhf(Cv / (nv + EPSv));
            out_h[idx] = hv;
            out_C[idx] = Cv;
            out_n[idx] = nv;
            h_bf[idx] = f2bf(hv);
        }
    }
}

// y GEMM: h_bf [16384][1024] @ WyT^T + by -> y [16384][1024] f32
__global__ __launch_bounds__(256)
void gemm_y(const unsigned short* __restrict__ A, const unsigned short* __restrict__ WyT,
            const float* __restrict__ by, float* __restrict__ y)
{
    __shared__ unsigned short sA[128 * 32], sB[128 * 32];
    const int t = threadIdx.x;
    // 1024 blocks = 128 row-blocks x 8 col-blocks
    const int swz = (blockIdx.x & 7) * 128 + (blockIdx.x >> 3);
    const int mblk = swz & 127, nblk = swz >> 7;
    const int m0 = mblk * 128, n0 = nblk * 128;

    f32x4 acc[4][4];
    #pragma unroll
    for (int i = 0; i < 4; ++i)
        #pragma unroll
        for (int j = 0; j < 4; ++j) acc[i][j] = (f32x4)0.f;

    mfma_loop(A, 1024, WyT, 1024, 1024, m0, n0, t, sA, sB, acc);

    const int lane = t & 63, wid = t >> 6;
    const int wr = wid >> 1, wc = wid & 1;
    const int cl = lane & 15, hi = lane >> 4;
    #pragma unroll
    for (int i = 0; i < 4; ++i) {
        const int rb = m0 + wr * 64 + i * 16 + hi * 4;
        #pragma unroll
        for (int jf = 0; jf < 4; ++jf) {
            const int c = n0 + wc * 64 + jf * 16 + cl;
            const float bc = by[c];
            #pragma unroll
            for (int r = 0; r < 4; ++r)
                y[(size_t)(rb + r) * 1024 + c] = acc[i][jf][r] + bc;
        }
    }
}

// ---------------- fallback f32 path (round-1 kernels) ----------------

constexpr int FBM = 64, FBN = 64, FBK = 16, FPAD = 4;

__global__ __launch_bounds__(256)
void fb_gates(const float* __restrict__ x, const float* __restrict__ h_prev,
              const float* __restrict__ c_prev, const float* __restrict__ n_prev,
              const float* __restrict__ Wz, const float* __restrict__ Rz,
              const float* __restrict__ Wi, const float* __restrict__ Ri,
              const float* __restrict__ Wf, const float* __restrict__ Rf,
              const float* __restrict__ Wo, const float* __restrict__ Ro,
              const float* __restrict__ bWz, const float* __restrict__ bRz, const float* __restrict__ bz,
              const float* __restrict__ bWi, const float* __restrict__ bRi, const float* __restrict__ bi,
              const float* __restrict__ bWf, const float* __restrict__ bRf, const float* __restrict__ bf_,
              const float* __restrict__ bWo, const float* __restrict__ bRo, const float* __restrict__ bo,
              float* __restrict__ out_h, float* __restrict__ out_C, float* __restrict__ out_n)
{
    __shared__ float sA[FBK][FBM + FPAD];
    __shared__ float sB[4][FBK][FBN + FPAD];
    const int t = threadIdx.x;
    const int col_blk = blockIdx.x & 15, row_blk = blockIdx.x >> 4;
    const int row0 = row_blk * FBM, col0 = col_blk * FBN;
    const int tx = t & 15, ty = t >> 4;
    float acc[4][4][4];
    #pragma unroll
    for (int g = 0; g < 4; ++g)
        for (int i = 0; i < 4; ++i)
            for (int j = 0; j < 4; ++j) acc[g][i][j] = 0.f;
    const int ar = t >> 2, ak = (t & 3) * 4, wk = t >> 4, wcc = (t & 15) * 4;
    for (int phase = 0; phase < 2; ++phase) {
        const float* Am = phase ? h_prev : x;
        const float* W0 = phase ? Rz : Wz; const float* W1 = phase ? Ri : Wi;
        const float* W2 = phase ? Rf : Wf; const float* W3 = phase ? Ro : Wo;
        for (int k0 = 0; k0 < 1024; k0 += FBK) {
            __syncthreads();
            {
                const float4 v = *(const float4*)(Am + (size_t)(row0 + ar) * 1024 + k0 + ak);
                sA[ak + 0][ar] = v.x; sA[ak + 1][ar] = v.y;
                sA[ak + 2][ar] = v.z; sA[ak + 3][ar] = v.w;
            }
            *(float4*)&sB[0][wk][wcc] = *(const float4*)(W0 + (size_t)(k0 + wk) * 1024 + col0 + wcc);
            *(float4*)&sB[1][wk][wcc] = *(const float4*)(W1 + (size_t)(k0 + wk) * 1024 + col0 + wcc);
            *(float4*)&sB[2][wk][wcc] = *(const float4*)(W2 + (size_t)(k0 + wk) * 1024 + col0 + wcc);
            *(float4*)&sB[3][wk][wcc] = *(const float4*)(W3 + (size_t)(k0 + wk) * 1024 + col0 + wcc);
            __syncthreads();
            #pragma unroll
            for (int kk = 0; kk < FBK; ++kk) {
                float a[4], bb[4][4];
                *(float4*)a = *(const float4*)&sA[kk][ty * 4];
                *(float4*)&bb[0][0] = *(const float4*)&sB[0][kk][tx * 4];
                *(float4*)&bb[1][0] = *(const float4*)&sB[1][kk][tx * 4];
                *(float4*)&bb[2][0] = *(const float4*)&sB[2][kk][tx * 4];
                *(float4*)&bb[3][0] = *(const float4*)&sB[3][kk][tx * 4];
                #pragma unroll
                for (int g = 0; g < 4; ++g)
                    for (int i = 0; i < 4; ++i)
                        for (int j = 0; j < 4; ++j)
                            acc[g][i][j] += a[i] * bb[g][j];
            }
        }
    }
    #pragma unroll
    for (int i = 0; i < 4; ++i) {
        const int r = row0 + ty * 4 + i;
        #pragma unroll
        for (int j = 0; j < 4; ++j) {
            const int c = col0 + tx * 4 + j;
            const float pz = acc[0][i][j] + bWz[c] + bRz[c] + bz[c];
            const float pi = acc[1][i][j] + bWi[c] + bRi[c] + bi[c];
            const float pf = acc[2][i][j] + bWf[c] + bRf[c] + bf_[c];
            const float po = acc[3][i][j] + bWo[c] + bRo[c] + bo[c];
            const float zt = tanhf(pz);
            const float it = expf(pi);
            const float ft = 1.f / (1.f + expf(-pf));
            const float ot = 1.f / (1.f + expf(-po));
            const size_t idx = (size_t)r * Hh + c;
            const float Cv = ft * c_prev[idx] + it * zt;
            const float nv = ft * n_prev[idx] + it;
            out_h[idx] = ot * tanhf(Cv / (nv + EPSv));
            out_C[idx] = Cv;
            out_n[idx] = nv;
        }
    }
}

__global__ __launch_bounds__(256)
void fb_ygemm(const float* __restrict__ hmat, const float* __restrict__ Wy,
              const float* __restrict__ by, float* __restrict__ y)
{
    __shared__ float sA[FBK][FBM + FPAD];
    __shared__ float sB[FBK][FBN + FPAD];
    const int t = threadIdx.x;
    const int col_blk = blockIdx.x & 15, row_blk = blockIdx.x >> 4;
    const int row0 = row_blk * FBM, col0 = col_blk * FBN;
    const int tx = t & 15, ty = t >> 4;
    float acc[4][4];
    #pragma unroll
    for (int i = 0; i < 4; ++i)
        for (int j = 0; j < 4; ++j) acc[i][j] = 0.f;
    const int ar = t >> 2, ak = (t & 3) * 4, wk = t >> 4, wcc = (t & 15) * 4;
    for (int k0 = 0; k0 < 1024; k0 += FBK) {
        __syncthreads();
        {
            const float4 v = *(const float4*)(hmat + (size_t)(row0 + ar) * 1024 + k0 + ak);
            sA[ak + 0][ar] = v.x; sA[ak + 1][ar] = v.y;
            sA[ak + 2][ar] = v.z; sA[ak + 3][ar] = v.w;
        }
        *(float4*)&sB[wk][wcc] = *(const float4*)(Wy + (size_t)(k0 + wk) * 1024 + col0 + wcc);
        __syncthreads();
        #pragma unroll
        for (int kk = 0; kk < FBK; ++kk) {
            float a[4], bb[4];
            *(float4*)a = *(const float4*)&sA[kk][ty * 4];
            *(float4*)bb = *(const float4*)&sB[kk][tx * 4];
            #pragma unroll
            for (int i = 0; i < 4; ++i)
                for (int j = 0; j < 4; ++j)
                    acc[i][j] += a[i] * bb[j];
        }
    }
    #pragma unroll
    for (int i = 0; i < 4; ++i) {
        const int r = row0 + ty * 4 + i;
        #pragma unroll
        for (int j = 0; j < 4; ++j) {
            const int c = col0 + tx * 4 + j;
            y[(size_t)r * Dd + c] = acc[i][j] + by[c];
        }
    }
}

// ---------------- launch ----------------

extern "C" void kernel_launch(void* const* d_in, const int* in_sizes, int n_in,
                              void* d_out, int out_size, void* d_ws, size_t ws_size,
                              hipStream_t stream) {
    const float* x      = (const float*)d_in[0];
    const float* h_prev = (const float*)d_in[1];
    const float* c_prev = (const float*)d_in[2];
    const float* n_prev = (const float*)d_in[3];
    const float* Wz  = (const float*)d_in[4];
    const float* bWz = (const float*)d_in[5];
    const float* Rz  = (const float*)d_in[6];
    const float* bRz = (const float*)d_in[7];
    const float* bz  = (const float*)d_in[8];
    const float* Wi  = (const float*)d_in[9];
    const float* bWi = (const float*)d_in[10];
    const float* Ri  = (const float*)d_in[11];
    const float* bRi = (const float*)d_in[12];
    const float* bi  = (const float*)d_in[13];
    const float* Wf  = (const float*)d_in[14];
    const float* bWf = (const float*)d_in[15];
    const float* Rf  = (const float*)d_in[16];
    const float* bRf = (const float*)d_in[17];
    const float* bf_ = (const float*)d_in[18];
    const float* Wo  = (const float*)d_in[19];
    const float* bWo = (const float*)d_in[20];
    const float* Ro  = (const float*)d_in[21];
    const float* bRo = (const float*)d_in[22];
    const float* bo  = (const float*)d_in[23];
    const float* Wy  = (const float*)d_in[24];
    const float* by  = (const float*)d_in[25];

    float* y     = (float*)d_out;
    float* out_h = y + (size_t)Bsz * Dd;
    float* out_C = out_h + (size_t)Bsz * Hh;
    float* out_n = out_C + (size_t)Bsz * Hh;

    // ws layout (bytes)
    const size_t OFF_A    = 0;           // 16384*2048*2 = 67108864
    const size_t OFF_WT   = 67108864;    // 4096*2048*2  = 16777216
    const size_t OFF_WYT  = 83886080;    // 1024*1024*2  = 2097152
    const size_t OFF_HBF  = 85983232;    // 16384*1024*2 = 33554432
    const size_t OFF_BS   = 119537664;   // 4*1024*4     = 16384
    const size_t WS_NEED  = 119554048;

    if (ws_size >= WS_NEED) {
        char* ws = (char*)d_ws;
        unsigned short* A_bf = (unsigned short*)(ws + OFF_A);
        unsigned short* WT   = (unsigned short*)(ws + OFF_WT);
        unsigned short* WyT  = (unsigned short*)(ws + OFF_WYT);
        unsigned short* h_bf = (unsigned short*)(ws + OFF_HBF);
        float* bsum          = (float*)(ws + OFF_BS);

        cvt_A<<<16384, 256, 0, stream>>>(x, h_prev, A_bf);
        // gates: g = 0:z 1:i 2:f 3:o ; W -> k [0,1024), R -> k [1024,2048)
        cvt_T<<<256, 256, 0, stream>>>(Wz, WT, 2048, 0,    0, 0);
        cvt_T<<<256, 256, 0, stream>>>(Rz, WT, 2048, 1024, 0, 0);
        cvt_T<<<256, 256, 0, stream>>>(Wi, WT, 2048, 0,    1, 0);
        cvt_T<<<256, 256, 0, stream>>>(Ri, WT, 2048, 1024, 1, 0);
        cvt_T<<<256, 256, 0, stream>>>(Wf, WT, 2048, 0,    2, 0);
        cvt_T<<<256, 256, 0, stream>>>(Rf, WT, 2048, 1024, 2, 0);
        cvt_T<<<256, 256, 0, stream>>>(Wo, WT, 2048, 0,    3, 0);
        cvt_T<<<256, 256, 0, stream>>>(Ro, WT, 2048, 1024, 3, 0);
        cvt_T<<<256, 256, 0, stream>>>(Wy, WyT, 1024, 0,   0, 1);
        bias_sum<<<4, 256, 0, stream>>>(bWz, bRz, bz, bWi, bRi, bi,
                                        bWf, bRf, bf_, bWo, bRo, bo, bsum);

        gemm_gates<<<4096, 256, 0, stream>>>(A_bf, WT, bsum, c_prev, n_prev,
                                             out_h, out_C, out_n, h_bf);
        gemm_y<<<1024, 256, 0, stream>>>(h_bf, WyT, by, y);
    } else {
        dim3 block(256);
        dim3 grid((Bsz / FBM) * (Hh / FBN));
        fb_gates<<<grid, block, 0, stream>>>(x, h_prev, c_prev, n_prev,
                                             Wz, Rz, Wi, Ri, Wf, Rf, Wo, Ro,
                                             bWz, bRz, bz, bWi, bRi, bi,
                                             bWf, bRf, bf_, bWo, bRo, bo,
                                             out_h, out_C, out_n);
        fb_ygemm<<<grid, block, 0, stream>>>(out_h, Wy, by, y);
    }
}

// Round 3
// 519.244 us; speedup vs baseline: 7.1096x; 1.1139x over previous
//
#include <hip/hip_runtime.h>
#include <math.h>
#include <stdint.h>

// sLSTM cell, B=16384, D=H=1024.
// bf16-MFMA path (needs ws >= ~114 MB):
//   cvt kernels build: A=[x|h_prev] bf16 [16384][2048], WT gate-interleaved bf16 [4096][2048],
//   WyT bf16 [1024][1024], bsum f32 [4][1024].
//   gemm_gates / gemm_y: 256x128-tile BK=64 triple-buffered counted-vmcnt MFMA GEMM
//   (T2 swizzle + T3/T4 deep pipeline + T5 setprio), fused gate epilogue.
// Fallback (small ws): round-1 f32 vector kernels.

typedef __attribute__((ext_vector_type(8))) short bf16x8;
typedef __attribute__((ext_vector_type(4))) float f32x4;

constexpr int Bsz = 16384;
constexpr int Dd  = 1024;
constexpr int Hh  = 1024;
constexpr float EPSv = 1e-7f;

__device__ __forceinline__ unsigned short f2bf(float f) {
    union { float f; uint32_t u; } v; v.f = f;
    uint32_t u = v.u + 0x7fffu + ((v.u >> 16) & 1u);   // RNE
    return (unsigned short)(u >> 16);
}

__device__ __forceinline__ void gload16(const void* g, void* l) {
    __builtin_amdgcn_global_load_lds(
        (const __attribute__((address_space(1))) void*)g,
        (__attribute__((address_space(3))) void*)l, 16, 0, 0);
}

// ---------------- conversion kernels ----------------

__global__ __launch_bounds__(256)
void cvt_A(const float* __restrict__ x, const float* __restrict__ hp, unsigned short* __restrict__ A)
{
    const int idx = blockIdx.x * 256 + threadIdx.x;   // 8 elements each
    const int n = idx * 8;
    const int b = n >> 11, k = n & 2047;
    const float* s = (k < 1024) ? (x + (size_t)b * 1024 + k)
                                : (hp + (size_t)b * 1024 + (k - 1024));
    const float4 v0 = *(const float4*)s;
    const float4 v1 = *(const float4*)(s + 4);
    union { unsigned short u[8]; uint4 v; } pk;
    pk.u[0] = f2bf(v0.x); pk.u[1] = f2bf(v0.y); pk.u[2] = f2bf(v0.z); pk.u[3] = f2bf(v0.w);
    pk.u[4] = f2bf(v1.x); pk.u[5] = f2bf(v1.y); pk.u[6] = f2bf(v1.z); pk.u[7] = f2bf(v1.w);
    *(uint4*)(A + n) = pk.v;
}

// src [1024][1024] f32 (rows=k, cols=j) -> dst[c'][kbase+k] bf16.
// mode 0: c' = (j&15)|(g<<4)|((j>>4)<<6)   (gate-interleaved)
// mode 1: c' = j
__global__ __launch_bounds__(256)
void cvt_T(const float* __restrict__ src, unsigned short* __restrict__ dst,
           int ldd, int kbase, int g, int mode)
{
    __shared__ float tile[64][65];
    const int t = threadIdx.x;
    const int kt = blockIdx.x & 15, jt = blockIdx.x >> 4;
    {
        const int lr = t >> 4, lc = (t & 15) * 4;
        #pragma unroll
        for (int rr = 0; rr < 64; rr += 16) {
            const float4 v = *(const float4*)(src + (size_t)(kt * 64 + rr + lr) * 1024 + jt * 64 + lc);
            tile[rr + lr][lc + 0] = v.x;
            tile[rr + lr][lc + 1] = v.y;
            tile[rr + lr][lc + 2] = v.z;
            tile[rr + lr][lc + 3] = v.w;
        }
    }
    __syncthreads();
    const int jl = t >> 2, kc = (t & 3) * 16;
    const int j = jt * 64 + jl;
    const int cp = mode ? j : ((j & 15) | (g << 4) | ((j >> 4) << 6));
    union { unsigned short u[16]; uint4 v[2]; } pk;
    #pragma unroll
    for (int q = 0; q < 16; ++q) pk.u[q] = f2bf(tile[kc + q][jl]);
    uint4* d = (uint4*)(dst + (size_t)cp * ldd + kbase + kt * 64 + kc);
    d[0] = pk.v[0];
    d[1] = pk.v[1];
}

__global__ __launch_bounds__(256)
void bias_sum(const float* bWz, const float* bRz, const float* bz,
              const float* bWi, const float* bRi, const float* bi,
              const float* bWf, const float* bRf, const float* bf_,
              const float* bWo, const float* bRo, const float* bo,
              float* __restrict__ bs)
{
    const int j = blockIdx.x * 256 + threadIdx.x;   // grid 4
    bs[j]        = bWz[j] + bRz[j] + bz[j];
    bs[1024 + j] = bWi[j] + bRi[j] + bi[j];
    bs[2048 + j] = bWf[j] + bRf[j] + bf_[j];
    bs[3072 + j] = bWo[j] + bRo[j] + bo[j];
}

// ---------------- MFMA GEMM core: 256x128 tile, BK=64, triple-buffered ----------------
// 512 threads = 8 waves (4 wave-rows x 2 wave-cols), per-wave output 64x64 = acc[4][4].
// LDS per buffer: A 256x64 bf16 (32KB) + B 128x64 bf16 (16KB); 3 buffers = 144KB.
// LDS swizzle: element (row,k), chunk=k/8 stored at chunk^(row&7)  [T2; conflict-free b128 reads]
//   -> staged via inverse-swizzled GLOBAL source + linear global_load_lds dest (rule #21).
// Pipeline: stage tile t+2 issued at top of tile t; vmcnt(6) + one barrier per tile (T4: never 0).

template<int LDA, int LDB, int KTOT>
__device__ __forceinline__ void mfma_core(const unsigned short* __restrict__ Ag,
                                          const unsigned short* __restrict__ Bg,
                                          int m0, int n0, int t,
                                          unsigned short* lds, f32x4 acc[4][4])
{
    constexpr int NT = KTOT / 64;
    const int srow = t >> 3;                    // 0..63: staged row within 64-row group
    const int seff = (t & 7) ^ (srow & 7);      // inverse-swizzled source chunk
    const int lane = t & 63;
    const int wid  = t >> 6;
    const int wr = wid >> 1, wc = wid & 1;      // 4x2 wave grid
    const int cl = lane & 15, hi = lane >> 4;
    const int chunk0 = hi ^ (cl & 7);           // swizzled read chunk, k-sub 0
    const int aBase = (wr * 64 + cl) * 64 + chunk0 * 8;           // shorts
    const int bBase = 16384 + (wc * 64 + cl) * 64 + chunk0 * 8;   // shorts

    auto stage = [&](int kt, int b) {
        const int k0 = kt * 64;
        const unsigned short* ga = Ag + (size_t)(m0 + srow) * LDA + k0 + seff * 8;
        const unsigned short* gb = Bg + (size_t)(n0 + srow) * LDB + k0 + seff * 8;
        unsigned short* l = lds + b * 24576 + t * 8;
        gload16(ga,             l);              // A rows   0- 63
        gload16(ga +  64 * LDA, l + 4096);       // A rows  64-127
        gload16(ga + 128 * LDA, l + 8192);       // A rows 128-191
        gload16(ga + 192 * LDA, l + 12288);      // A rows 192-255
        gload16(gb,             l + 16384);      // B cols   0- 63
        gload16(gb +  64 * LDB, l + 20480);      // B cols  64-127
    };

    stage(0, 0);
    stage(1, 1);
    asm volatile("s_waitcnt vmcnt(6)" ::: "memory");   // tile 0 landed
    __builtin_amdgcn_s_barrier();
    asm volatile("" ::: "memory");

    for (int tt = 0; tt < NT; ++tt) {
        const unsigned short* bA = lds + (tt % 3) * 24576;
        int kt = tt + 2; if (kt > NT - 1) kt = NT - 1;   // tail: redundant re-stage, never read
        stage(kt, (tt + 2) % 3);
        #pragma unroll
        for (int s = 0; s < 2; ++s) {
            const int sx = s * 32;                        // k-sub toggle: chunk ^= 4 (bit 5 of short-offset)
            bf16x8 av[4], bv[4];
            #pragma unroll
            for (int i = 0; i < 4; ++i)
                av[i] = *(const bf16x8*)(bA + ((aBase + i * 1024) ^ sx));
            #pragma unroll
            for (int j = 0; j < 2; ++j)
                bv[j] = *(const bf16x8*)(bA + ((bBase + j * 1024) ^ sx));
            __builtin_amdgcn_s_setprio(1);
            #pragma unroll
            for (int i = 0; i < 4; ++i)
                #pragma unroll
                for (int j = 0; j < 2; ++j)
                    acc[i][j] = __builtin_amdgcn_mfma_f32_16x16x32_bf16(av[i], bv[j], acc[i][j], 0, 0, 0);
            __builtin_amdgcn_s_setprio(0);
            #pragma unroll
            for (int j = 2; j < 4; ++j)
                bv[j] = *(const bf16x8*)(bA + ((bBase + j * 1024) ^ sx));
            __builtin_amdgcn_s_setprio(1);
            #pragma unroll
            for (int i = 0; i < 4; ++i)
                #pragma unroll
                for (int j = 2; j < 4; ++j)
                    acc[i][j] = __builtin_amdgcn_mfma_f32_16x16x32_bf16(av[i], bv[j], acc[i][j], 0, 0, 0);
            __builtin_amdgcn_s_setprio(0);
        }
        asm volatile("s_waitcnt vmcnt(6)" ::: "memory");  // next tile landed; t+2's 6 still in flight
        __builtin_amdgcn_s_barrier();
        asm volatile("" ::: "memory");
    }
    asm volatile("s_waitcnt vmcnt(0)" ::: "memory");      // drain tail stages before endpgm
}

// gates GEMM: A [16384][2048] bf16, WT [4096][2048] bf16 (gate-interleaved cols).
__global__ __launch_bounds__(512, 2)
void gemm_gates(const unsigned short* __restrict__ A, const unsigned short* __restrict__ WT,
                const float* __restrict__ bsum,
                const float* __restrict__ c_prev, const float* __restrict__ n_prev,
                float* __restrict__ out_h, float* __restrict__ out_C, float* __restrict__ out_n,
                unsigned short* __restrict__ h_bf)
{
    __shared__ unsigned short lds[3 * 24576];   // 144 KB
    const int t = threadIdx.x;
    // grid 2048 = 64 mblk x 32 nblk; XCD swizzle (2048 % 8 == 0), nblk fast (A-panel reuse in L2)
    const int swz = (blockIdx.x & 7) * 256 + (blockIdx.x >> 3);
    const int nblk = swz & 31, mblk = swz >> 5;
    const int m0 = mblk * 256, n0 = nblk * 128;

    f32x4 acc[4][4];
    #pragma unroll
    for (int i = 0; i < 4; ++i)
        #pragma unroll
        for (int j = 0; j < 4; ++j) acc[i][j] = (f32x4)0.f;

    mfma_core<2048, 2048, 2048>(A, WT, m0, n0, t, lds, acc);

    // epilogue: lane-local gate combine. Wave's 4 col-frags = 4 gates of the same 16 cols.
    const int lane = t & 63, wid = t >> 6;
    const int wr = wid >> 1, wc = wid & 1;
    const int cl = lane & 15, hi = lane >> 4;
    const int j_out = (nblk * 2 + wc) * 16 + cl;     // output column 0..1023
    const float bz_ = bsum[j_out];
    const float bi_ = bsum[1024 + j_out];
    const float bf_ = bsum[2048 + j_out];
    const float bo_ = bsum[3072 + j_out];
    #pragma unroll
    for (int i = 0; i < 4; ++i) {
        const int rb = m0 + wr * 64 + i * 16 + hi * 4;
        #pragma unroll
        for (int r = 0; r < 4; ++r) {
            const size_t idx = (size_t)(rb + r) * 1024 + j_out;
            const float pz = acc[i][0][r] + bz_;
            const float pi = acc[i][1][r] + bi_;
            const float pf = acc[i][2][r] + bf_;
            const float po = acc[i][3][r] + bo_;
            const float zt = tanhf(pz);
            const float it = expf(pi);
            const float ft = 1.f / (1.f + expf(-pf));
            const float ot = 1.f / (1.f + expf(-po));
            const float Cv = ft * c_prev[idx] + it * zt;
            const float nv = ft * n_prev[idx] + it;
            const float hv = ot * tanhf(Cv / (nv + EPSv));
            out_h[idx] = hv;
            out_C[idx] = Cv;
            out_n[idx] = nv;
            h_bf[idx] = f2bf(hv);
        }
    }
}

// y GEMM: h_bf [16384][1024] @ WyT^T + by -> y [16384][1024] f32
__global__ __launch_bounds__(512, 2)
void gemm_y(const unsigned short* __restrict__ A, const unsigned short* __restrict__ WyT,
            const float* __restrict__ by, float* __restrict__ y)
{
    __shared__ unsigned short lds[3 * 24576];
    const int t = threadIdx.x;
    // grid 512 = 64 mblk x 8 nblk
    const int swz = (blockIdx.x & 7) * 64 + (blockIdx.x >> 3);
    const int nblk = swz & 7, mblk = swz >> 3;
    const int m0 = mblk * 256, n0 = nblk * 128;

    f32x4 acc[4][4];
    #pragma unroll
    for (int i = 0; i < 4; ++i)
        #pragma unroll
        for (int j = 0; j < 4; ++j) acc[i][j] = (f32x4)0.f;

    mfma_core<1024, 1024, 1024>(A, WyT, m0, n0, t, lds, acc);

    const int lane = t & 63, wid = t >> 6;
    const int wr = wid >> 1, wc = wid & 1;
    const int cl = lane & 15, hi = lane >> 4;
    #pragma unroll
    for (int i = 0; i < 4; ++i) {
        const int rb = m0 + wr * 64 + i * 16 + hi * 4;
        #pragma unroll
        for (int jf = 0; jf < 4; ++jf) {
            const int c = n0 + wc * 64 + jf * 16 + cl;
            const float bc = by[c];
            #pragma unroll
            for (int r = 0; r < 4; ++r)
                y[(size_t)(rb + r) * 1024 + c] = acc[i][jf][r] + bc;
        }
    }
}

// ---------------- fallback f32 path (round-1 kernels) ----------------

constexpr int FBM = 64, FBN = 64, FBK = 16, FPAD = 4;

__global__ __launch_bounds__(256)
void fb_gates(const float* __restrict__ x, const float* __restrict__ h_prev,
              const float* __restrict__ c_prev, const float* __restrict__ n_prev,
              const float* __restrict__ Wz, const float* __restrict__ Rz,
              const float* __restrict__ Wi, const float* __restrict__ Ri,
              const float* __restrict__ Wf, const float* __restrict__ Rf,
              const float* __restrict__ Wo, const float* __restrict__ Ro,
              const float* __restrict__ bWz, const float* __restrict__ bRz, const float* __restrict__ bz,
              const float* __restrict__ bWi, const float* __restrict__ bRi, const float* __restrict__ bi,
              const float* __restrict__ bWf, const float* __restrict__ bRf, const float* __restrict__ bf_,
              const float* __restrict__ bWo, const float* __restrict__ bRo, const float* __restrict__ bo,
              float* __restrict__ out_h, float* __restrict__ out_C, float* __restrict__ out_n)
{
    __shared__ float sA[FBK][FBM + FPAD];
    __shared__ float sB[4][FBK][FBN + FPAD];
    const int t = threadIdx.x;
    const int col_blk = blockIdx.x & 15, row_blk = blockIdx.x >> 4;
    const int row0 = row_blk * FBM, col0 = col_blk * FBN;
    const int tx = t & 15, ty = t >> 4;
    float acc[4][4][4];
    #pragma unroll
    for (int g = 0; g < 4; ++g)
        for (int i = 0; i < 4; ++i)
            for (int j = 0; j < 4; ++j) acc[g][i][j] = 0.f;
    const int ar = t >> 2, ak = (t & 3) * 4, wk = t >> 4, wcc = (t & 15) * 4;
    for (int phase = 0; phase < 2; ++phase) {
        const float* Am = phase ? h_prev : x;
        const float* W0 = phase ? Rz : Wz; const float* W1 = phase ? Ri : Wi;
        const float* W2 = phase ? Rf : Wf; const float* W3 = phase ? Ro : Wo;
        for (int k0 = 0; k0 < 1024; k0 += FBK) {
            __syncthreads();
            {
                const float4 v = *(const float4*)(Am + (size_t)(row0 + ar) * 1024 + k0 + ak);
                sA[ak + 0][ar] = v.x; sA[ak + 1][ar] = v.y;
                sA[ak + 2][ar] = v.z; sA[ak + 3][ar] = v.w;
            }
            *(float4*)&sB[0][wk][wcc] = *(const float4*)(W0 + (size_t)(k0 + wk) * 1024 + col0 + wcc);
            *(float4*)&sB[1][wk][wcc] = *(const float4*)(W1 + (size_t)(k0 + wk) * 1024 + col0 + wcc);
            *(float4*)&sB[2][wk][wcc] = *(const float4*)(W2 + (size_t)(k0 + wk) * 1024 + col0 + wcc);
            *(float4*)&sB[3][wk][wcc] = *(const float4*)(W3 + (size_t)(k0 + wk) * 1024 + col0 + wcc);
            __syncthreads();
            #pragma unroll
            for (int kk = 0; kk < FBK; ++kk) {
                float a[4], bb[4][4];
                *(float4*)a = *(const float4*)&sA[kk][ty * 4];
                *(float4*)&bb[0][0] = *(const float4*)&sB[0][kk][tx * 4];
                *(float4*)&bb[1][0] = *(const float4*)&sB[1][kk][tx * 4];
                *(float4*)&bb[2][0] = *(const float4*)&sB[2][kk][tx * 4];
                *(float4*)&bb[3][0] = *(const float4*)&sB[3][kk][tx * 4];
                #pragma unroll
                for (int g = 0; g < 4; ++g)
                    for (int i = 0; i < 4; ++i)
                        for (int j = 0; j < 4; ++j)
                            acc[g][i][j] += a[i] * bb[g][j];
            }
        }
    }
    #pragma unroll
    for (int i = 0; i < 4; ++i) {
        const int r = row0 + ty * 4 + i;
        #pragma unroll
        for (int j = 0; j < 4; ++j) {
            const int c = col0 + tx * 4 + j;
            const float pz = acc[0][i][j] + bWz[c] + bRz[c] + bz[c];
            const float pi = acc[1][i][j] + bWi[c] + bRi[c] + bi[c];
            const float pf = acc[2][i][j] + bWf[c] + bRf[c] + bf_[c];
            const float po = acc[3][i][j] + bWo[c] + bRo[c] + bo[c];
            const float zt = tanhf(pz);
            const float it = expf(pi);
            const float ft = 1.f / (1.f + expf(-pf));
            const float ot = 1.f / (1.f + expf(-po));
            const size_t idx = (size_t)r * Hh + c;
            const float Cv = ft * c_prev[idx] + it * zt;
            const float nv = ft * n_prev[idx] + it;
            out_h[idx] = ot * tanhf(Cv / (nv + EPSv));
            out_C[idx] = Cv;
            out_n[idx] = nv;
        }
    }
}

__global__ __launch_bounds__(256)
void fb_ygemm(const float* __restrict__ hmat, const float* __restrict__ Wy,
              const float* __restrict__ by, float* __restrict__ y)
{
    __shared__ float sA[FBK][FBM + FPAD];
    __shared__ float sB[FBK][FBN + FPAD];
    const int t = threadIdx.x;
    const int col_blk = blockIdx.x & 15, row_blk = blockIdx.x >> 4;
    const int row0 = row_blk * FBM, col0 = col_blk * FBN;
    const int tx = t & 15, ty = t >> 4;
    float acc[4][4];
    #pragma unroll
    for (int i = 0; i < 4; ++i)
        for (int j = 0; j < 4; ++j) acc[i][j] = 0.f;
    const int ar = t >> 2, ak = (t & 3) * 4, wk = t >> 4, wcc = (t & 15) * 4;
    for (int k0 = 0; k0 < 1024; k0 += FBK) {
        __syncthreads();
        {
            const float4 v = *(const float4*)(hmat + (size_t)(row0 + ar) * 1024 + k0 + ak);
            sA[ak + 0][ar] = v.x; sA[ak + 1][ar] = v.y;
            sA[ak + 2][ar] = v.z; sA[ak + 3][ar] = v.w;
        }
        *(float4*)&sB[wk][wcc] = *(const float4*)(Wy + (size_t)(k0 + wk) * 1024 + col0 + wcc);
        __syncthreads();
        #pragma unroll
        for (int kk = 0; kk < FBK; ++kk) {
            float a[4], bb[4];
            *(float4*)a = *(const float4*)&sA[kk][ty * 4];
            *(float4*)bb = *(const float4*)&sB[kk][tx * 4];
            #pragma unroll
            for (int i = 0; i < 4; ++i)
                for (int j = 0; j < 4; ++j)
                    acc[i][j] += a[i] * bb[j];
        }
    }
    #pragma unroll
    for (int i = 0; i < 4; ++i) {
        const int r = row0 + ty * 4 + i;
        #pragma unroll
        for (int j = 0; j < 4; ++j) {
            const int c = col0 + tx * 4 + j;
            y[(size_t)r * Dd + c] = acc[i][j] + by[c];
        }
    }
}

// ---------------- launch ----------------

extern "C" void kernel_launch(void* const* d_in, const int* in_sizes, int n_in,
                              void* d_out, int out_size, void* d_ws, size_t ws_size,
                              hipStream_t stream) {
    const float* x      = (const float*)d_in[0];
    const float* h_prev = (const float*)d_in[1];
    const float* c_prev = (const float*)d_in[2];
    const float* n_prev = (const float*)d_in[3];
    const float* Wz  = (const float*)d_in[4];
    const float* bWz = (const float*)d_in[5];
    const float* Rz  = (const float*)d_in[6];
    const float* bRz = (const float*)d_in[7];
    const float* bz  = (const float*)d_in[8];
    const float* Wi  = (const float*)d_in[9];
    const float* bWi = (const float*)d_in[10];
    const float* Ri  = (const float*)d_in[11];
    const float* bRi = (const float*)d_in[12];
    const float* bi  = (const float*)d_in[13];
    const float* Wf  = (const float*)d_in[14];
    const float* bWf = (const float*)d_in[15];
    const float* Rf  = (const float*)d_in[16];
    const float* bRf = (const float*)d_in[17];
    const float* bf_ = (const float*)d_in[18];
    const float* Wo  = (const float*)d_in[19];
    const float* bWo = (const float*)d_in[20];
    const float* Ro  = (const float*)d_in[21];
    const float* bRo = (const float*)d_in[22];
    const float* bo  = (const float*)d_in[23];
    const float* Wy  = (const float*)d_in[24];
    const float* by  = (const float*)d_in[25];

    float* y     = (float*)d_out;
    float* out_h = y + (size_t)Bsz * Dd;
    float* out_C = out_h + (size_t)Bsz * Hh;
    float* out_n = out_C + (size_t)Bsz * Hh;

    // ws layout (bytes)
    const size_t OFF_A    = 0;           // 16384*2048*2 = 67108864
    const size_t OFF_WT   = 67108864;    // 4096*2048*2  = 16777216
    const size_t OFF_WYT  = 83886080;    // 1024*1024*2  = 2097152
    const size_t OFF_HBF  = 85983232;    // 16384*1024*2 = 33554432
    const size_t OFF_BS   = 119537664;   // 4*1024*4     = 16384
    const size_t WS_NEED  = 119554048;

    if (ws_size >= WS_NEED) {
        char* ws = (char*)d_ws;
        unsigned short* A_bf = (unsigned short*)(ws + OFF_A);
        unsigned short* WT   = (unsigned short*)(ws + OFF_WT);
        unsigned short* WyT  = (unsigned short*)(ws + OFF_WYT);
        unsigned short* h_bf = (unsigned short*)(ws + OFF_HBF);
        float* bsum          = (float*)(ws + OFF_BS);

        cvt_A<<<16384, 256, 0, stream>>>(x, h_prev, A_bf);
        // gates: g = 0:z 1:i 2:f 3:o ; W -> k [0,1024), R -> k [1024,2048)
        cvt_T<<<256, 256, 0, stream>>>(Wz, WT, 2048, 0,    0, 0);
        cvt_T<<<256, 256, 0, stream>>>(Rz, WT, 2048, 1024, 0, 0);
        cvt_T<<<256, 256, 0, stream>>>(Wi, WT, 2048, 0,    1, 0);
        cvt_T<<<256, 256, 0, stream>>>(Ri, WT, 2048, 1024, 1, 0);
        cvt_T<<<256, 256, 0, stream>>>(Wf, WT, 2048, 0,    2, 0);
        cvt_T<<<256, 256, 0, stream>>>(Rf, WT, 2048, 1024, 2, 0);
        cvt_T<<<256, 256, 0, stream>>>(Wo, WT, 2048, 0,    3, 0);
        cvt_T<<<256, 256, 0, stream>>>(Ro, WT, 2048, 1024, 3, 0);
        cvt_T<<<256, 256, 0, stream>>>(Wy, WyT, 1024, 0,   0, 1);
        bias_sum<<<4, 256, 0, stream>>>(bWz, bRz, bz, bWi, bRi, bi,
                                        bWf, bRf, bf_, bWo, bRo, bo, bsum);

        gemm_gates<<<2048, 512, 0, stream>>>(A_bf, WT, bsum, c_prev, n_prev,
                                             out_h, out_C, out_n, h_bf);
        gemm_y<<<512, 512, 0, stream>>>(h_bf, WyT, by, y);
    } else {
        dim3 block(256);
        dim3 grid((Bsz / FBM) * (Hh / FBN));
        fb_gates<<<grid, block, 0, stream>>>(x, h_prev, c_prev, n_prev,
                                             Wz, Rz, Wi, Ri, Wf, Rf, Wo, Ro,
                                             bWz, bRz, bz, bWi, bRi, bi,
                                             bWf, bRf, bf_, bWo, bRo, bo,
                                             out_h, out_C, out_n);
        fb_ygemm<<<grid, block, 0, stream>>>(out_h, Wy, by, y);
    }
}

// Round 4
// 466.220 us; speedup vs baseline: 7.9181x; 1.1137x over previous
//
#include <hip/hip_runtime.h>
#include <math.h>
#include <stdint.h>

// sLSTM cell, B=16384, D=H=1024.
// bf16-MFMA path (needs ws >= ~114 MB):
//   cvt kernels build: A=[x|h_prev] bf16 [16384][2048], WT gate-interleaved bf16 [4096][2048],
//   WyT bf16 [1024][1024], bsum f32 [4][1024].
//   gemm_gates / gemm_y: m201-style 256x256-tile BK=64 8-phase double-buffered MFMA GEMM
//   (T2 swizzle + T3/T4 counted-vmcnt 8-phase pipeline + T5 setprio), fused gate epilogue.
// Fallback (small ws): round-1 f32 vector kernels.

typedef __attribute__((ext_vector_type(8))) short bf16x8;
typedef __attribute__((ext_vector_type(4))) float f32x4;

constexpr int Bsz = 16384;
constexpr int Dd  = 1024;
constexpr int Hh  = 1024;
constexpr float EPSv = 1e-7f;

__device__ __forceinline__ unsigned short f2bf(float f) {
    union { float f; uint32_t u; } v; v.f = f;
    uint32_t u = v.u + 0x7fffu + ((v.u >> 16) & 1u);   // RNE
    return (unsigned short)(u >> 16);
}

__device__ __forceinline__ void gload16(const void* g, void* l) {
    __builtin_amdgcn_global_load_lds(
        (const __attribute__((address_space(1))) void*)g,
        (__attribute__((address_space(3))) void*)l, 16, 0, 0);
}

// ---------------- conversion kernels ----------------

__global__ __launch_bounds__(256)
void cvt_A(const float* __restrict__ x, const float* __restrict__ hp, unsigned short* __restrict__ A)
{
    const int idx = blockIdx.x * 256 + threadIdx.x;   // 8 elements each
    const int n = idx * 8;
    const int b = n >> 11, k = n & 2047;
    const float* s = (k < 1024) ? (x + (size_t)b * 1024 + k)
                                : (hp + (size_t)b * 1024 + (k - 1024));
    const float4 v0 = *(const float4*)s;
    const float4 v1 = *(const float4*)(s + 4);
    union { unsigned short u[8]; uint4 v; } pk;
    pk.u[0] = f2bf(v0.x); pk.u[1] = f2bf(v0.y); pk.u[2] = f2bf(v0.z); pk.u[3] = f2bf(v0.w);
    pk.u[4] = f2bf(v1.x); pk.u[5] = f2bf(v1.y); pk.u[6] = f2bf(v1.z); pk.u[7] = f2bf(v1.w);
    *(uint4*)(A + n) = pk.v;
}

// src [1024][1024] f32 (rows=k, cols=j) -> dst[c'][kbase+k] bf16.
// mode 0: c' = (j&15)|(g<<4)|((j>>4)<<6)   (gate-interleaved)
// mode 1: c' = j
__global__ __launch_bounds__(256)
void cvt_T(const float* __restrict__ src, unsigned short* __restrict__ dst,
           int ldd, int kbase, int g, int mode)
{
    __shared__ float tile[64][65];
    const int t = threadIdx.x;
    const int kt = blockIdx.x & 15, jt = blockIdx.x >> 4;
    {
        const int lr = t >> 4, lc = (t & 15) * 4;
        #pragma unroll
        for (int rr = 0; rr < 64; rr += 16) {
            const float4 v = *(const float4*)(src + (size_t)(kt * 64 + rr + lr) * 1024 + jt * 64 + lc);
            tile[rr + lr][lc + 0] = v.x;
            tile[rr + lr][lc + 1] = v.y;
            tile[rr + lr][lc + 2] = v.z;
            tile[rr + lr][lc + 3] = v.w;
        }
    }
    __syncthreads();
    const int jl = t >> 2, kc = (t & 3) * 16;
    const int j = jt * 64 + jl;
    const int cp = mode ? j : ((j & 15) | (g << 4) | ((j >> 4) << 6));
    union { unsigned short u[16]; uint4 v[2]; } pk;
    #pragma unroll
    for (int q = 0; q < 16; ++q) pk.u[q] = f2bf(tile[kc + q][jl]);
    uint4* d = (uint4*)(dst + (size_t)cp * ldd + kbase + kt * 64 + kc);
    d[0] = pk.v[0];
    d[1] = pk.v[1];
}

__global__ __launch_bounds__(256)
void bias_sum(const float* bWz, const float* bRz, const float* bz,
              const float* bWi, const float* bRi, const float* bi,
              const float* bWf, const float* bRf, const float* bf_,
              const float* bWo, const float* bRo, const float* bo,
              float* __restrict__ bs)
{
    const int j = blockIdx.x * 256 + threadIdx.x;   // grid 4
    bs[j]        = bWz[j] + bRz[j] + bz[j];
    bs[1024 + j] = bWi[j] + bRi[j] + bi[j];
    bs[2048 + j] = bWf[j] + bRf[j] + bf_[j];
    bs[3072 + j] = bWo[j] + bRo[j] + bo[j];
}

// ---------------- MFMA GEMM core: 256x256 tile, BK=64, 8-phase double-buffered ----------------
// 512 threads = 8 waves (2 wave-rows x 4 wave-cols). Per-wave output 128x64 = acc[8][4].
// LDS per buffer: A 256x64 bf16 (32KB) + B 256x64 bf16 (32KB); 2 buffers = 128KB.
// Swizzle (T2): element (row,k), chunk=k/8 stored at chunk^(row&7); staged via
//   inverse-swizzled GLOBAL source + linear global_load_lds dest (rule #21). 0 conflicts (R3).
// Schedule per iteration (2 K-tiles: 2it->buf0, 2it+1->buf1), 8 phases:
//   P1: rdB(b0,k0)+rdA(b0,mh0,k0) | stage buf1.Amh0(t1) | bar | lgkm0 | 16 MFMA | bar
//   P2: rdB(b0,k1)+rdA(b0,mh0,k1) | stage buf1.Amh1(t1) | ...
//   P3: rdA(b0,mh1,k0)            | stage buf0.Bh0(t2)  | ...
//   P4: rdA(b0,mh1,k1)            | stage buf0.Bh1(t2)  | vmcnt(4) | ...
//   P5..P8: same on buf1, staging buf0.Amh0/mh1(t2), buf1.Bh0/Bh1(t3), vmcnt(4) at P8.
// vmcnt(4) = 2 loads/phase x 2 younger phases (T4: never 0 in-loop).

template<int LDA, int LDB, int KTOT>
__device__ __forceinline__ void mfma8(const unsigned short* __restrict__ Ag,
                                      const unsigned short* __restrict__ Bg,
                                      int m0, int n0, int t,
                                      unsigned short* lds, f32x4 acc[8][4])
{
    constexpr int NT = KTOT / 64;
    constexpr int NI = NT / 2;
    const int lane = t & 63, wid = t >> 6;
    const int wr = wid >> 2, wc = wid & 3;
    const int cl = lane & 15, hi = lane >> 4;
    const int aB = (wr * 128 + cl) * 64 + ((hi ^ (cl & 7)) << 3);
    const int bB = 16384 + (wc * 64 + cl) * 64 + ((hi ^ (cl & 7)) << 3);
    const int srow = t >> 3;
    const int schk = ((t & 7) ^ (srow & 7)) << 3;
    const unsigned short* gA = Ag + (size_t)(m0 + srow) * LDA + schk;
    const unsigned short* gB = Bg + (size_t)(n0 + srow) * LDB + schk;
    unsigned short* ldst = lds + t * 8;

    bf16x8 Ar[4], Br[4][2];

#define STG_A(kt, h, b) { const unsigned short* g_ = gA + (size_t)((h) * 128) * LDA + (kt) * 64; \
    unsigned short* l_ = ldst + (b) * 32768 + (h) * 8192; \
    gload16(g_, l_); gload16(g_ + (size_t)64 * LDA, l_ + 4096); }
#define STG_B(kt, h, b) { const unsigned short* g_ = gB + (size_t)((h) * 128) * LDB + (kt) * 64; \
    unsigned short* l_ = ldst + (b) * 32768 + 16384 + (h) * 8192; \
    gload16(g_, l_); gload16(g_ + (size_t)64 * LDB, l_ + 4096); }
#define RD_A(b, mh, ks) { _Pragma("unroll") for (int mm = 0; mm < 4; ++mm) \
    Ar[mm] = *(const bf16x8*)(lds + (b) * 32768 + ((aB + (mh) * 4096 + mm * 1024) ^ ((ks) * 32))); }
#define RD_B(b, ks) { _Pragma("unroll") for (int nn = 0; nn < 4; ++nn) \
    Br[nn][ks] = *(const bf16x8*)(lds + (b) * 32768 + ((bB + nn * 1024) ^ ((ks) * 32))); }
#define MM(mh, ks) { __builtin_amdgcn_s_setprio(1); \
    _Pragma("unroll") for (int mm = 0; mm < 4; ++mm) \
    _Pragma("unroll") for (int nn = 0; nn < 4; ++nn) \
    acc[(mh) * 4 + mm][nn] = __builtin_amdgcn_mfma_f32_16x16x32_bf16(Ar[mm], Br[nn][ks], acc[(mh) * 4 + mm][nn], 0, 0, 0); \
    __builtin_amdgcn_s_setprio(0); }
#define BAR() __builtin_amdgcn_s_barrier()
#define LGKM0() { asm volatile("s_waitcnt lgkmcnt(0)" ::: "memory"); __builtin_amdgcn_sched_barrier(0); }
#define VMW(n) asm volatile("s_waitcnt vmcnt(" #n ")" ::: "memory")

    // prologue: tile0 -> buf0 (8 loads), tile1.B -> buf1 (4 loads)
    STG_B(0, 0, 0); STG_B(0, 1, 0); STG_A(0, 0, 0); STG_A(0, 1, 0);
    STG_B(1, 0, 1); STG_B(1, 1, 1);
    VMW(4); BAR();

    for (int it = 0; it < NI; ++it) {
        const int t1 = 2 * it + 1;
        int t2 = 2 * it + 2; if (t2 >= NT) t2 = NT - 1;
        int t3 = 2 * it + 3; if (t3 >= NT) t3 = NT - 1;
        // P1
        RD_B(0, 0); RD_A(0, 0, 0); STG_A(t1, 0, 1); BAR(); LGKM0(); MM(0, 0); BAR();
        // P2
        RD_B(0, 1); RD_A(0, 0, 1); STG_A(t1, 1, 1); BAR(); LGKM0(); MM(0, 1); BAR();
        // P3
        RD_A(0, 1, 0); STG_B(t2, 0, 0); BAR(); LGKM0(); MM(1, 0); BAR();
        // P4
        RD_A(0, 1, 1); STG_B(t2, 1, 0); VMW(4); BAR(); LGKM0(); MM(1, 1); BAR();
        // P5
        RD_B(1, 0); RD_A(1, 0, 0); STG_A(t2, 0, 0); BAR(); LGKM0(); MM(0, 0); BAR();
        // P6
        RD_B(1, 1); RD_A(1, 0, 1); STG_A(t2, 1, 0); BAR(); LGKM0(); MM(0, 1); BAR();
        // P7
        RD_A(1, 1, 0); STG_B(t3, 0, 1); BAR(); LGKM0(); MM(1, 0); BAR();
        // P8
        RD_A(1, 1, 1); STG_B(t3, 1, 1); VMW(4); BAR(); LGKM0(); MM(1, 1); BAR();
    }
    VMW(0);   // drain tail junk stages

#undef STG_A
#undef STG_B
#undef RD_A
#undef RD_B
#undef MM
#undef BAR
#undef LGKM0
#undef VMW
}

// gates GEMM: A [16384][2048] bf16, WT [4096][2048] bf16 (gate-interleaved cols).
__global__ __launch_bounds__(512, 2)
void gemm_gates(const unsigned short* __restrict__ A, const unsigned short* __restrict__ WT,
                const float* __restrict__ bsum,
                const float* __restrict__ c_prev, const float* __restrict__ n_prev,
                float* __restrict__ out_h, float* __restrict__ out_C, float* __restrict__ out_n,
                unsigned short* __restrict__ h_bf)
{
    __shared__ unsigned short lds[65536];   // 128 KB
    const int t = threadIdx.x;
    // grid 1024 = 64 mblk x 16 nblk; XCD swizzle (1024 % 8 == 0), mblk-fast (W-panel L2-resident)
    const int swz = (blockIdx.x & 7) * 128 + (blockIdx.x >> 3);
    const int mblk = swz & 63, nblk = swz >> 6;
    const int m0 = mblk * 256, n0 = nblk * 256;

    f32x4 acc[8][4];
    #pragma unroll
    for (int i = 0; i < 8; ++i)
        #pragma unroll
        for (int j = 0; j < 4; ++j) acc[i][j] = (f32x4)0.f;

    mfma8<2048, 2048, 2048>(A, WT, m0, n0, t, lds, acc);

    // epilogue: lane-local gate combine. Wave's 4 n-frags = 4 gates of the same 16 cols.
    const int lane = t & 63, wid = t >> 6;
    const int wr = wid >> 2, wc = wid & 3;
    const int cl = lane & 15, hi = lane >> 4;
    const int j_out = (nblk * 4 + wc) * 16 + cl;     // output column 0..1023
    const float bz_ = bsum[j_out];
    const float bi_ = bsum[1024 + j_out];
    const float bf_ = bsum[2048 + j_out];
    const float bo_ = bsum[3072 + j_out];
    #pragma unroll
    for (int mf = 0; mf < 8; ++mf) {
        const int rb = m0 + wr * 128 + mf * 16 + hi * 4;
        #pragma unroll
        for (int r = 0; r < 4; ++r) {
            const size_t idx = (size_t)(rb + r) * 1024 + j_out;
            const float pz = acc[mf][0][r] + bz_;
            const float pi = acc[mf][1][r] + bi_;
            const float pf = acc[mf][2][r] + bf_;
            const float po = acc[mf][3][r] + bo_;
            const float zt = tanhf(pz);
            const float it = expf(pi);
            const float ft = 1.f / (1.f + expf(-pf));
            const float ot = 1.f / (1.f + expf(-po));
            const float Cv = ft * c_prev[idx] + it * zt;
            const float nv = ft * n_prev[idx] + it;
            const float hv = ot * tanhf(Cv / (nv + EPSv));
            out_h[idx] = hv;
            out_C[idx] = Cv;
            out_n[idx] = nv;
            h_bf[idx] = f2bf(hv);
        }
    }
}

// y GEMM: h_bf [16384][1024] @ WyT^T + by -> y [16384][1024] f32
__global__ __launch_bounds__(512, 2)
void gemm_y(const unsigned short* __restrict__ A, const unsigned short* __restrict__ WyT,
            const float* __restrict__ by, float* __restrict__ y)
{
    __shared__ unsigned short lds[65536];
    const int t = threadIdx.x;
    // grid 256 = 64 mblk x 4 nblk
    const int swz = (blockIdx.x & 7) * 32 + (blockIdx.x >> 3);
    const int mblk = swz & 63, nblk = swz >> 6;
    const int m0 = mblk * 256, n0 = nblk * 256;

    f32x4 acc[8][4];
    #pragma unroll
    for (int i = 0; i < 8; ++i)
        #pragma unroll
        for (int j = 0; j < 4; ++j) acc[i][j] = (f32x4)0.f;

    mfma8<1024, 1024, 1024>(A, WyT, m0, n0, t, lds, acc);

    const int lane = t & 63, wid = t >> 6;
    const int wr = wid >> 2, wc = wid & 3;
    const int cl = lane & 15, hi = lane >> 4;
    #pragma unroll
    for (int mf = 0; mf < 8; ++mf) {
        const int rb = m0 + wr * 128 + mf * 16 + hi * 4;
        #pragma unroll
        for (int nf = 0; nf < 4; ++nf) {
            const int c = n0 + wc * 64 + nf * 16 + cl;
            const float bc = by[c];
            #pragma unroll
            for (int r = 0; r < 4; ++r)
                y[(size_t)(rb + r) * 1024 + c] = acc[mf][nf][r] + bc;
        }
    }
}

// ---------------- fallback f32 path (round-1 kernels) ----------------

constexpr int FBM = 64, FBN = 64, FBK = 16, FPAD = 4;

__global__ __launch_bounds__(256)
void fb_gates(const float* __restrict__ x, const float* __restrict__ h_prev,
              const float* __restrict__ c_prev, const float* __restrict__ n_prev,
              const float* __restrict__ Wz, const float* __restrict__ Rz,
              const float* __restrict__ Wi, const float* __restrict__ Ri,
              const float* __restrict__ Wf, const float* __restrict__ Rf,
              const float* __restrict__ Wo, const float* __restrict__ Ro,
              const float* __restrict__ bWz, const float* __restrict__ bRz, const float* __restrict__ bz,
              const float* __restrict__ bWi, const float* __restrict__ bRi, const float* __restrict__ bi,
              const float* __restrict__ bWf, const float* __restrict__ bRf, const float* __restrict__ bf_,
              const float* __restrict__ bWo, const float* __restrict__ bRo, const float* __restrict__ bo,
              float* __restrict__ out_h, float* __restrict__ out_C, float* __restrict__ out_n)
{
    __shared__ float sA[FBK][FBM + FPAD];
    __shared__ float sB[4][FBK][FBN + FPAD];
    const int t = threadIdx.x;
    const int col_blk = blockIdx.x & 15, row_blk = blockIdx.x >> 4;
    const int row0 = row_blk * FBM, col0 = col_blk * FBN;
    const int tx = t & 15, ty = t >> 4;
    float acc[4][4][4];
    #pragma unroll
    for (int g = 0; g < 4; ++g)
        for (int i = 0; i < 4; ++i)
            for (int j = 0; j < 4; ++j) acc[g][i][j] = 0.f;
    const int ar = t >> 2, ak = (t & 3) * 4, wk = t >> 4, wcc = (t & 15) * 4;
    for (int phase = 0; phase < 2; ++phase) {
        const float* Am = phase ? h_prev : x;
        const float* W0 = phase ? Rz : Wz; const float* W1 = phase ? Ri : Wi;
        const float* W2 = phase ? Rf : Wf; const float* W3 = phase ? Ro : Wo;
        for (int k0 = 0; k0 < 1024; k0 += FBK) {
            __syncthreads();
            {
                const float4 v = *(const float4*)(Am + (size_t)(row0 + ar) * 1024 + k0 + ak);
                sA[ak + 0][ar] = v.x; sA[ak + 1][ar] = v.y;
                sA[ak + 2][ar] = v.z; sA[ak + 3][ar] = v.w;
            }
            *(float4*)&sB[0][wk][wcc] = *(const float4*)(W0 + (size_t)(k0 + wk) * 1024 + col0 + wcc);
            *(float4*)&sB[1][wk][wcc] = *(const float4*)(W1 + (size_t)(k0 + wk) * 1024 + col0 + wcc);
            *(float4*)&sB[2][wk][wcc] = *(const float4*)(W2 + (size_t)(k0 + wk) * 1024 + col0 + wcc);
            *(float4*)&sB[3][wk][wcc] = *(const float4*)(W3 + (size_t)(k0 + wk) * 1024 + col0 + wcc);
            __syncthreads();
            #pragma unroll
            for (int kk = 0; kk < FBK; ++kk) {
                float a[4], bb[4][4];
                *(float4*)a = *(const float4*)&sA[kk][ty * 4];
                *(float4*)&bb[0][0] = *(const float4*)&sB[0][kk][tx * 4];
                *(float4*)&bb[1][0] = *(const float4*)&sB[1][kk][tx * 4];
                *(float4*)&bb[2][0] = *(const float4*)&sB[2][kk][tx * 4];
                *(float4*)&bb[3][0] = *(const float4*)&sB[3][kk][tx * 4];
                #pragma unroll
                for (int g = 0; g < 4; ++g)
                    for (int i = 0; i < 4; ++i)
                        for (int j = 0; j < 4; ++j)
                            acc[g][i][j] += a[i] * bb[g][j];
            }
        }
    }
    #pragma unroll
    for (int i = 0; i < 4; ++i) {
        const int r = row0 + ty * 4 + i;
        #pragma unroll
        for (int j = 0; j < 4; ++j) {
            const int c = col0 + tx * 4 + j;
            const float pz = acc[0][i][j] + bWz[c] + bRz[c] + bz[c];
            const float pi = acc[1][i][j] + bWi[c] + bRi[c] + bi[c];
            const float pf = acc[2][i][j] + bWf[c] + bRf[c] + bf_[c];
            const float po = acc[3][i][j] + bWo[c] + bRo[c] + bo[c];
            const float zt = tanhf(pz);
            const float it = expf(pi);
            const float ft = 1.f / (1.f + expf(-pf));
            const float ot = 1.f / (1.f + expf(-po));
            const size_t idx = (size_t)r * Hh + c;
            const float Cv = ft * c_prev[idx] + it * zt;
            const float nv = ft * n_prev[idx] + it;
            out_h[idx] = ot * tanhf(Cv / (nv + EPSv));
            out_C[idx] = Cv;
            out_n[idx] = nv;
        }
    }
}

__global__ __launch_bounds__(256)
void fb_ygemm(const float* __restrict__ hmat, const float* __restrict__ Wy,
              const float* __restrict__ by, float* __restrict__ y)
{
    __shared__ float sA[FBK][FBM + FPAD];
    __shared__ float sB[FBK][FBN + FPAD];
    const int t = threadIdx.x;
    const int col_blk = blockIdx.x & 15, row_blk = blockIdx.x >> 4;
    const int row0 = row_blk * FBM, col0 = col_blk * FBN;
    const int tx = t & 15, ty = t >> 4;
    float acc[4][4];
    #pragma unroll
    for (int i = 0; i < 4; ++i)
        for (int j = 0; j < 4; ++j) acc[i][j] = 0.f;
    const int ar = t >> 2, ak = (t & 3) * 4, wk = t >> 4, wcc = (t & 15) * 4;
    for (int k0 = 0; k0 < 1024; k0 += FBK) {
        __syncthreads();
        {
            const float4 v = *(const float4*)(hmat + (size_t)(row0 + ar) * 1024 + k0 + ak);
            sA[ak + 0][ar] = v.x; sA[ak + 1][ar] = v.y;
            sA[ak + 2][ar] = v.z; sA[ak + 3][ar] = v.w;
        }
        *(float4*)&sB[wk][wcc] = *(const float4*)(Wy + (size_t)(k0 + wk) * 1024 + col0 + wcc);
        __syncthreads();
        #pragma unroll
        for (int kk = 0; kk < FBK; ++kk) {
            float a[4], bb[4];
            *(float4*)a = *(const float4*)&sA[kk][ty * 4];
            *(float4*)bb = *(const float4*)&sB[kk][tx * 4];
            #pragma unroll
            for (int i = 0; i < 4; ++i)
                for (int j = 0; j < 4; ++j)
                    acc[i][j] += a[i] * bb[j];
        }
    }
    #pragma unroll
    for (int i = 0; i < 4; ++i) {
        const int r = row0 + ty * 4 + i;
        #pragma unroll
        for (int j = 0; j < 4; ++j) {
            const int c = col0 + tx * 4 + j;
            y[(size_t)r * Dd + c] = acc[i][j] + by[c];
        }
    }
}

// ---------------- launch ----------------

extern "C" void kernel_launch(void* const* d_in, const int* in_sizes, int n_in,
                              void* d_out, int out_size, void* d_ws, size_t ws_size,
                              hipStream_t stream) {
    const float* x      = (const float*)d_in[0];
    const float* h_prev = (const float*)d_in[1];
    const float* c_prev = (const float*)d_in[2];
    const float* n_prev = (const float*)d_in[3];
    const float* Wz  = (const float*)d_in[4];
    const float* bWz = (const float*)d_in[5];
    const float* Rz  = (const float*)d_in[6];
    const float* bRz = (const float*)d_in[7];
    const float* bz  = (const float*)d_in[8];
    const float* Wi  = (const float*)d_in[9];
    const float* bWi = (const float*)d_in[10];
    const float* Ri  = (const float*)d_in[11];
    const float* bRi = (const float*)d_in[12];
    const float* bi  = (const float*)d_in[13];
    const float* Wf  = (const float*)d_in[14];
    const float* bWf = (const float*)d_in[15];
    const float* Rf  = (const float*)d_in[16];
    const float* bRf = (const float*)d_in[17];
    const float* bf_ = (const float*)d_in[18];
    const float* Wo  = (const float*)d_in[19];
    const float* bWo = (const float*)d_in[20];
    const float* Ro  = (const float*)d_in[21];
    const float* bRo = (const float*)d_in[22];
    const float* bo  = (const float*)d_in[23];
    const float* Wy  = (const float*)d_in[24];
    const float* by  = (const float*)d_in[25];

    float* y     = (float*)d_out;
    float* out_h = y + (size_t)Bsz * Dd;
    float* out_C = out_h + (size_t)Bsz * Hh;
    float* out_n = out_C + (size_t)Bsz * Hh;

    // ws layout (bytes)
    const size_t OFF_A    = 0;           // 16384*2048*2 = 67108864
    const size_t OFF_WT   = 67108864;    // 4096*2048*2  = 16777216
    const size_t OFF_WYT  = 83886080;    // 1024*1024*2  = 2097152
    const size_t OFF_HBF  = 85983232;    // 16384*1024*2 = 33554432
    const size_t OFF_BS   = 119537664;   // 4*1024*4     = 16384
    const size_t WS_NEED  = 119554048;

    if (ws_size >= WS_NEED) {
        char* ws = (char*)d_ws;
        unsigned short* A_bf = (unsigned short*)(ws + OFF_A);
        unsigned short* WT   = (unsigned short*)(ws + OFF_WT);
        unsigned short* WyT  = (unsigned short*)(ws + OFF_WYT);
        unsigned short* h_bf = (unsigned short*)(ws + OFF_HBF);
        float* bsum          = (float*)(ws + OFF_BS);

        cvt_A<<<16384, 256, 0, stream>>>(x, h_prev, A_bf);
        // gates: g = 0:z 1:i 2:f 3:o ; W -> k [0,1024), R -> k [1024,2048)
        cvt_T<<<256, 256, 0, stream>>>(Wz, WT, 2048, 0,    0, 0);
        cvt_T<<<256, 256, 0, stream>>>(Rz, WT, 2048, 1024, 0, 0);
        cvt_T<<<256, 256, 0, stream>>>(Wi, WT, 2048, 0,    1, 0);
        cvt_T<<<256, 256, 0, stream>>>(Ri, WT, 2048, 1024, 1, 0);
        cvt_T<<<256, 256, 0, stream>>>(Wf, WT, 2048, 0,    2, 0);
        cvt_T<<<256, 256, 0, stream>>>(Rf, WT, 2048, 1024, 2, 0);
        cvt_T<<<256, 256, 0, stream>>>(Wo, WT, 2048, 0,    3, 0);
        cvt_T<<<256, 256, 0, stream>>>(Ro, WT, 2048, 1024, 3, 0);
        cvt_T<<<256, 256, 0, stream>>>(Wy, WyT, 1024, 0,   0, 1);
        bias_sum<<<4, 256, 0, stream>>>(bWz, bRz, bz, bWi, bRi, bi,
                                        bWf, bRf, bf_, bWo, bRo, bo, bsum);

        gemm_gates<<<1024, 512, 0, stream>>>(A_bf, WT, bsum, c_prev, n_prev,
                                             out_h, out_C, out_n, h_bf);
        gemm_y<<<256, 512, 0, stream>>>(h_bf, WyT, by, y);
    } else {
        dim3 block(256);
        dim3 grid((Bsz / FBM) * (Hh / FBN));
        fb_gates<<<grid, block, 0, stream>>>(x, h_prev, c_prev, n_prev,
                                             Wz, Rz, Wi, Ri, Wf, Rf, Wo, Ro,
                                             bWz, bRz, bz, bWi, bRi, bi,
                                             bWf, bRf, bf_, bWo, bRo, bo,
                                             out_h, out_C, out_n);
        fb_ygemm<<<grid, block, 0, stream>>>(out_h, Wy, by, y);
    }
}

// Round 5
// 451.428 us; speedup vs baseline: 8.1776x; 1.0328x over previous
//
#include <hip/hip_runtime.h>
#include <math.h>
#include <stdint.h>

// sLSTM cell, B=16384, D=H=1024.
// bf16-MFMA path (needs ws >= ~114 MB):
//   cvt kernels build: A=[x|h_prev] bf16 [16384][2048], WT gate-interleaved bf16 [4096][2048],
//   WyT bf16 [1024][1024], bsum f32 [4][1024].
//   gemm_gates / gemm_y: 256x256-tile BK=64 double-buffered MFMA GEMM with grouped
//   counted-lgkm sections (compiler-counted waits), persistent tile chaining,
//   T2 swizzle + T4 counted vmcnt + T5 setprio. Fused gate epilogue.
// Fallback (small ws): round-1 f32 vector kernels.

typedef __attribute__((ext_vector_type(8))) short bf16x8;
typedef __attribute__((ext_vector_type(4))) float f32x4;

constexpr int Bsz = 16384;
constexpr int Dd  = 1024;
constexpr int Hh  = 1024;
constexpr float EPSv = 1e-7f;

__device__ __forceinline__ unsigned short f2bf(float f) {
    union { float f; uint32_t u; } v; v.f = f;
    uint32_t u = v.u + 0x7fffu + ((v.u >> 16) & 1u);   // RNE
    return (unsigned short)(u >> 16);
}

__device__ __forceinline__ void gload16(const void* g, void* l) {
    __builtin_amdgcn_global_load_lds(
        (const __attribute__((address_space(1))) void*)g,
        (__attribute__((address_space(3))) void*)l, 16, 0, 0);
}

// ---------------- conversion kernels ----------------

__global__ __launch_bounds__(256)
void cvt_A(const float* __restrict__ x, const float* __restrict__ hp, unsigned short* __restrict__ A)
{
    const int idx = blockIdx.x * 256 + threadIdx.x;   // 8 elements each
    const int n = idx * 8;
    const int b = n >> 11, k = n & 2047;
    const float* s = (k < 1024) ? (x + (size_t)b * 1024 + k)
                                : (hp + (size_t)b * 1024 + (k - 1024));
    const float4 v0 = *(const float4*)s;
    const float4 v1 = *(const float4*)(s + 4);
    union { unsigned short u[8]; uint4 v; } pk;
    pk.u[0] = f2bf(v0.x); pk.u[1] = f2bf(v0.y); pk.u[2] = f2bf(v0.z); pk.u[3] = f2bf(v0.w);
    pk.u[4] = f2bf(v1.x); pk.u[5] = f2bf(v1.y); pk.u[6] = f2bf(v1.z); pk.u[7] = f2bf(v1.w);
    *(uint4*)(A + n) = pk.v;
}

// src [1024][1024] f32 (rows=k, cols=j) -> dst[c'][kbase+k] bf16.
// mode 0: c' = (j&15)|(g<<4)|((j>>4)<<6)   (gate-interleaved)
// mode 1: c' = j
__global__ __launch_bounds__(256)
void cvt_T(const float* __restrict__ src, unsigned short* __restrict__ dst,
           int ldd, int kbase, int g, int mode)
{
    __shared__ float tile[64][65];
    const int t = threadIdx.x;
    const int kt = blockIdx.x & 15, jt = blockIdx.x >> 4;
    {
        const int lr = t >> 4, lc = (t & 15) * 4;
        #pragma unroll
        for (int rr = 0; rr < 64; rr += 16) {
            const float4 v = *(const float4*)(src + (size_t)(kt * 64 + rr + lr) * 1024 + jt * 64 + lc);
            tile[rr + lr][lc + 0] = v.x;
            tile[rr + lr][lc + 1] = v.y;
            tile[rr + lr][lc + 2] = v.z;
            tile[rr + lr][lc + 3] = v.w;
        }
    }
    __syncthreads();
    const int jl = t >> 2, kc = (t & 3) * 16;
    const int j = jt * 64 + jl;
    const int cp = mode ? j : ((j & 15) | (g << 4) | ((j >> 4) << 6));
    union { unsigned short u[16]; uint4 v[2]; } pk;
    #pragma unroll
    for (int q = 0; q < 16; ++q) pk.u[q] = f2bf(tile[kc + q][jl]);
    uint4* d = (uint4*)(dst + (size_t)cp * ldd + kbase + kt * 64 + kc);
    d[0] = pk.v[0];
    d[1] = pk.v[1];
}

__global__ __launch_bounds__(256)
void bias_sum(const float* bWz, const float* bRz, const float* bz,
              const float* bWi, const float* bRi, const float* bi,
              const float* bWf, const float* bRf, const float* bf_,
              const float* bWo, const float* bRo, const float* bo,
              float* __restrict__ bs)
{
    const int j = blockIdx.x * 256 + threadIdx.x;   // grid 4
    bs[j]        = bWz[j] + bRz[j] + bz[j];
    bs[1024 + j] = bWi[j] + bRi[j] + bi[j];
    bs[2048 + j] = bWf[j] + bRf[j] + bf_[j];
    bs[3072 + j] = bWo[j] + bRo[j] + bo[j];
}

// ---------------- MFMA GEMM core: 256x256 tile, BK=64, grouped sections, chained ----------------
// 512 threads = 8 waves (2 wave-rows x 4 wave-cols). Per-wave output 128x64 = acc[8][4].
// LDS: 2 buffers x (A 256x64 + B 256x64) bf16 = 128KB. Swizzle: chunk^(row&7) (T2, 0 conflicts).
// Section (one K-tile): issue all 24 ds_reads in consumption order; compiler emits counted
// lgkm waits so read drain overlaps MFMA. 2 barriers/section. vmcnt(4)/section (T4, never 0).
// Chaining: NTILES output tiles per block (m varies, n fixed) share one warm pipeline.

template<int LDA, int NT, int NTILES, class Epi>
__device__ void mfma_chain(const unsigned short* __restrict__ Ag,
                           const unsigned short* __restrict__ Bg,
                           int m0base, int n0, int t,
                           unsigned short* lds, Epi epi)
{
    constexpr int TOT = NT * NTILES;
    const int lane = t & 63, wid = t >> 6;
    const int wr = wid >> 2, wc = wid & 3;
    const int cl = lane & 15, hi = lane >> 4;
    const int aB = (wr * 128 + cl) * 64 + ((hi ^ (cl & 7)) << 3);
    const int bB = 16384 + (wc * 64 + cl) * 64 + ((hi ^ (cl & 7)) << 3);
    const int srow = t >> 3;
    const int schk = ((t & 7) ^ (srow & 7)) << 3;
    unsigned short* ldst = lds + t * 8;

    f32x4 acc[8][4];
    #pragma unroll
    for (int i = 0; i < 8; ++i)
        #pragma unroll
        for (int j = 0; j < 4; ++j) acc[i][j] = (f32x4)0.f;

    auto stgA = [&](int fi, int buf) {   // full A-tile of flat K-tile fi -> buf (4 loads)
        const int ot = fi / NT, kt = fi % NT;
        const unsigned short* g = Ag + (size_t)(m0base + ot * 256 + srow) * LDA + kt * 64 + schk;
        unsigned short* l = ldst + buf * 32768;
        gload16(g,                    l);
        gload16(g + (size_t) 64 * LDA, l + 4096);
        gload16(g + (size_t)128 * LDA, l + 8192);
        gload16(g + (size_t)192 * LDA, l + 12288);
    };
    auto stgB = [&](int fi, int buf) {   // full B-tile (n0 fixed across chain) (4 loads)
        const int kt = fi % NT;
        const unsigned short* g = Bg + (size_t)(n0 + srow) * LDA + kt * 64 + schk;
        unsigned short* l = ldst + buf * 32768 + 16384;
        gload16(g,                    l);
        gload16(g + (size_t) 64 * LDA, l + 4096);
        gload16(g + (size_t)128 * LDA, l + 8192);
        gload16(g + (size_t)192 * LDA, l + 12288);
    };

    // prologue: T0 -> buf0 (8 loads), T1.B -> buf1 (4 loads)
    stgA(0, 0); stgB(0, 0); stgB(1, 1);
    asm volatile("s_waitcnt vmcnt(4)" ::: "memory");   // T0 landed; T1.B in flight
    __builtin_amdgcn_s_barrier();

    for (int fi = 0; fi < TOT; ++fi) {
        const int bufR = fi & 1;
        const unsigned short* L = lds + bufR * 32768;
        int f1 = fi + 1; if (f1 > TOT - 1) f1 = TOT - 1;
        int f2 = fi + 2; if (f2 > TOT - 1) f2 = TOT - 1;

        bf16x8 Br0[4], Br1[4], Ar00[4], Ar01[4], Ar10[4], Ar11[4];
        #pragma unroll
        for (int nn = 0; nn < 4; ++nn) Br0[nn]  = *(const bf16x8*)(L + (bB + nn * 1024));
        #pragma unroll
        for (int mm = 0; mm < 4; ++mm) Ar00[mm] = *(const bf16x8*)(L + (aB + mm * 1024));

        stgA(f1, bufR ^ 1);                        // next tile's A -> other buffer

        #pragma unroll
        for (int nn = 0; nn < 4; ++nn) Br1[nn]  = *(const bf16x8*)(L + ((bB + nn * 1024) ^ 32));
        #pragma unroll
        for (int mm = 0; mm < 4; ++mm) Ar01[mm] = *(const bf16x8*)(L + ((aB + mm * 1024) ^ 32));

        __builtin_amdgcn_s_setprio(1);
        #pragma unroll
        for (int mm = 0; mm < 4; ++mm)
            #pragma unroll
            for (int nn = 0; nn < 4; ++nn)
                acc[mm][nn] = __builtin_amdgcn_mfma_f32_16x16x32_bf16(Ar00[mm], Br0[nn], acc[mm][nn], 0, 0, 0);
        __builtin_amdgcn_s_setprio(0);

        #pragma unroll
        for (int mm = 0; mm < 4; ++mm) Ar10[mm] = *(const bf16x8*)(L + (aB + 4096 + mm * 1024));
        #pragma unroll
        for (int mm = 0; mm < 4; ++mm) Ar11[mm] = *(const bf16x8*)(L + ((aB + 4096 + mm * 1024) ^ 32));

        __builtin_amdgcn_s_setprio(1);
        #pragma unroll
        for (int mm = 0; mm < 4; ++mm)
            #pragma unroll
            for (int nn = 0; nn < 4; ++nn)
                acc[mm][nn] = __builtin_amdgcn_mfma_f32_16x16x32_bf16(Ar01[mm], Br1[nn], acc[mm][nn], 0, 0, 0);
        __builtin_amdgcn_s_setprio(0);

        __builtin_amdgcn_sched_barrier(0);
        __builtin_amdgcn_s_barrier();              // all waves consumed B (Br0,Br1) + A-mh0

        stgB(f2, bufR);                            // restage this buffer's B region (safe now)

        __builtin_amdgcn_s_setprio(1);
        #pragma unroll
        for (int mm = 0; mm < 4; ++mm)
            #pragma unroll
            for (int nn = 0; nn < 4; ++nn)
                acc[4 + mm][nn] = __builtin_amdgcn_mfma_f32_16x16x32_bf16(Ar10[mm], Br0[nn], acc[4 + mm][nn], 0, 0, 0);
        __builtin_amdgcn_s_setprio(0);
        __builtin_amdgcn_s_setprio(1);
        #pragma unroll
        for (int mm = 0; mm < 4; ++mm)
            #pragma unroll
            for (int nn = 0; nn < 4; ++nn)
                acc[4 + mm][nn] = __builtin_amdgcn_mfma_f32_16x16x32_bf16(Ar11[mm], Br1[nn], acc[4 + mm][nn], 0, 0, 0);
        __builtin_amdgcn_s_setprio(0);

        __builtin_amdgcn_sched_barrier(0);
        asm volatile("s_waitcnt vmcnt(4)" ::: "memory");   // f1's A landed; f2's B in flight
        __builtin_amdgcn_s_barrier();

        if ((fi % NT) == NT - 1) {
            epi(fi / NT, acc);
            #pragma unroll
            for (int i = 0; i < 8; ++i)
                #pragma unroll
                for (int j = 0; j < 4; ++j) acc[i][j] = (f32x4)0.f;
        }
    }
    asm volatile("s_waitcnt vmcnt(0)" ::: "memory");   // drain tail junk stages
}

// gates GEMM: A [16384][2048] bf16, WT [4096][2048] bf16 (gate-interleaved cols).
// grid 256 = 1 block/CU; each block chains 4 m-tiles at fixed n-panel.
__global__ __launch_bounds__(512, 2)
void gemm_gates(const unsigned short* __restrict__ A, const unsigned short* __restrict__ WT,
                const float* __restrict__ bsum,
                const float* __restrict__ c_prev, const float* __restrict__ n_prev,
                float* __restrict__ out_h, float* __restrict__ out_C, float* __restrict__ out_n,
                unsigned short* __restrict__ h_bf)
{
    __shared__ unsigned short lds[65536];   // 128 KB
    const int t = threadIdx.x;
    const int b = blockIdx.x;               // 256 blocks
    // XCD-aware: xcd = b&7 sees 2 n-panels (2MB, L2-resident); m-chunk varies.
    const int nb  = (b & 7) * 2 + (b >> 7);         // 0..15
    const int mb0 = ((b >> 3) & 15) * 4;            // 0,4,...,60 ; tiles mb0..mb0+3
    const int m0base = mb0 * 256;
    const int n0 = nb * 256;

    const int lane = t & 63, wid = t >> 6;
    const int wr = wid >> 2, wc = wid & 3;
    const int cl = lane & 15, hi = lane >> 4;
    const int j_out = nb * 64 + wc * 16 + cl;       // output column 0..1023
    const float bz_ = bsum[j_out];
    const float bi_ = bsum[1024 + j_out];
    const float bf_ = bsum[2048 + j_out];
    const float bo_ = bsum[3072 + j_out];

    auto epi = [&](int ot, f32x4 (&acc)[8][4]) {
        #pragma unroll
        for (int mf = 0; mf < 8; ++mf) {
            const int rb = m0base + ot * 256 + wr * 128 + mf * 16 + hi * 4;
            #pragma unroll
            for (int r = 0; r < 4; ++r) {
                const size_t idx = (size_t)(rb + r) * 1024 + j_out;
                const float pz = acc[mf][0][r] + bz_;
                const float pi = acc[mf][1][r] + bi_;
                const float pf = acc[mf][2][r] + bf_;
                const float po = acc[mf][3][r] + bo_;
                const float zt = tanhf(pz);
                const float it = expf(pi);
                const float ft = 1.f / (1.f + expf(-pf));
                const float ot_ = 1.f / (1.f + expf(-po));
                const float Cv = ft * c_prev[idx] + it * zt;
                const float nv = ft * n_prev[idx] + it;
                const float hv = ot_ * tanhf(Cv / (nv + EPSv));
                out_h[idx] = hv;
                out_C[idx] = Cv;
                out_n[idx] = nv;
                h_bf[idx] = f2bf(hv);
            }
        }
    };

    mfma_chain<2048, 32, 4>(A, WT, m0base, n0, t, lds, epi);
}

// y GEMM: h_bf [16384][1024] @ WyT^T + by -> y [16384][1024] f32. grid 256, 1 tile/block.
__global__ __launch_bounds__(512, 2)
void gemm_y(const unsigned short* __restrict__ A, const unsigned short* __restrict__ WyT,
            const float* __restrict__ by, float* __restrict__ y)
{
    __shared__ unsigned short lds[65536];
    const int t = threadIdx.x;
    const int b = blockIdx.x;               // 256 = 64 mb x 4 nb
    const int nb = b & 3, mb = b >> 2;
    const int m0base = mb * 256, n0 = nb * 256;

    const int lane = t & 63, wid = t >> 6;
    const int wr = wid >> 2, wc = wid & 3;
    const int cl = lane & 15, hi = lane >> 4;

    auto epi = [&](int ot, f32x4 (&acc)[8][4]) {
        (void)ot;
        #pragma unroll
        for (int mf = 0; mf < 8; ++mf) {
            const int rb = m0base + wr * 128 + mf * 16 + hi * 4;
            #pragma unroll
            for (int nf = 0; nf < 4; ++nf) {
                const int c = n0 + wc * 64 + nf * 16 + cl;
                const float bc = by[c];
                #pragma unroll
                for (int r = 0; r < 4; ++r)
                    y[(size_t)(rb + r) * 1024 + c] = acc[mf][nf][r] + bc;
            }
        }
    };

    mfma_chain<1024, 16, 1>(A, WyT, m0base, n0, t, lds, epi);
}

// ---------------- fallback f32 path (round-1 kernels) ----------------

constexpr int FBM = 64, FBN = 64, FBK = 16, FPAD = 4;

__global__ __launch_bounds__(256)
void fb_gates(const float* __restrict__ x, const float* __restrict__ h_prev,
              const float* __restrict__ c_prev, const float* __restrict__ n_prev,
              const float* __restrict__ Wz, const float* __restrict__ Rz,
              const float* __restrict__ Wi, const float* __restrict__ Ri,
              const float* __restrict__ Wf, const float* __restrict__ Rf,
              const float* __restrict__ Wo, const float* __restrict__ Ro,
              const float* __restrict__ bWz, const float* __restrict__ bRz, const float* __restrict__ bz,
              const float* __restrict__ bWi, const float* __restrict__ bRi, const float* __restrict__ bi,
              const float* __restrict__ bWf, const float* __restrict__ bRf, const float* __restrict__ bf_,
              const float* __restrict__ bWo, const float* __restrict__ bRo, const float* __restrict__ bo,
              float* __restrict__ out_h, float* __restrict__ out_C, float* __restrict__ out_n)
{
    __shared__ float sA[FBK][FBM + FPAD];
    __shared__ float sB[4][FBK][FBN + FPAD];
    const int t = threadIdx.x;
    const int col_blk = blockIdx.x & 15, row_blk = blockIdx.x >> 4;
    const int row0 = row_blk * FBM, col0 = col_blk * FBN;
    const int tx = t & 15, ty = t >> 4;
    float acc[4][4][4];
    #pragma unroll
    for (int g = 0; g < 4; ++g)
        for (int i = 0; i < 4; ++i)
            for (int j = 0; j < 4; ++j) acc[g][i][j] = 0.f;
    const int ar = t >> 2, ak = (t & 3) * 4, wk = t >> 4, wcc = (t & 15) * 4;
    for (int phase = 0; phase < 2; ++phase) {
        const float* Am = phase ? h_prev : x;
        const float* W0 = phase ? Rz : Wz; const float* W1 = phase ? Ri : Wi;
        const float* W2 = phase ? Rf : Wf; const float* W3 = phase ? Ro : Wo;
        for (int k0 = 0; k0 < 1024; k0 += FBK) {
            __syncthreads();
            {
                const float4 v = *(const float4*)(Am + (size_t)(row0 + ar) * 1024 + k0 + ak);
                sA[ak + 0][ar] = v.x; sA[ak + 1][ar] = v.y;
                sA[ak + 2][ar] = v.z; sA[ak + 3][ar] = v.w;
            }
            *(float4*)&sB[0][wk][wcc] = *(const float4*)(W0 + (size_t)(k0 + wk) * 1024 + col0 + wcc);
            *(float4*)&sB[1][wk][wcc] = *(const float4*)(W1 + (size_t)(k0 + wk) * 1024 + col0 + wcc);
            *(float4*)&sB[2][wk][wcc] = *(const float4*)(W2 + (size_t)(k0 + wk) * 1024 + col0 + wcc);
            *(float4*)&sB[3][wk][wcc] = *(const float4*)(W3 + (size_t)(k0 + wk) * 1024 + col0 + wcc);
            __syncthreads();
            #pragma unroll
            for (int kk = 0; kk < FBK; ++kk) {
                float a[4], bb[4][4];
                *(float4*)a = *(const float4*)&sA[kk][ty * 4];
                *(float4*)&bb[0][0] = *(const float4*)&sB[0][kk][tx * 4];
                *(float4*)&bb[1][0] = *(const float4*)&sB[1][kk][tx * 4];
                *(float4*)&bb[2][0] = *(const float4*)&sB[2][kk][tx * 4];
                *(float4*)&bb[3][0] = *(const float4*)&sB[3][kk][tx * 4];
                #pragma unroll
                for (int g = 0; g < 4; ++g)
                    for (int i = 0; i < 4; ++i)
                        for (int j = 0; j < 4; ++j)
                            acc[g][i][j] += a[i] * bb[g][j];
            }
        }
    }
    #pragma unroll
    for (int i = 0; i < 4; ++i) {
        const int r = row0 + ty * 4 + i;
        #pragma unroll
        for (int j = 0; j < 4; ++j) {
            const int c = col0 + tx * 4 + j;
            const float pz = acc[0][i][j] + bWz[c] + bRz[c] + bz[c];
            const float pi = acc[1][i][j] + bWi[c] + bRi[c] + bi[c];
            const float pf = acc[2][i][j] + bWf[c] + bRf[c] + bf_[c];
            const float po = acc[3][i][j] + bWo[c] + bRo[c] + bo[c];
            const float zt = tanhf(pz);
            const float it = expf(pi);
            const float ft = 1.f / (1.f + expf(-pf));
            const float ot = 1.f / (1.f + expf(-po));
            const size_t idx = (size_t)r * Hh + c;
            const float Cv = ft * c_prev[idx] + it * zt;
            const float nv = ft * n_prev[idx] + it;
            out_h[idx] = ot * tanhf(Cv / (nv + EPSv));
            out_C[idx] = Cv;
            out_n[idx] = nv;
        }
    }
}

__global__ __launch_bounds__(256)
void fb_ygemm(const float* __restrict__ hmat, const float* __restrict__ Wy,
              const float* __restrict__ by, float* __restrict__ y)
{
    __shared__ float sA[FBK][FBM + FPAD];
    __shared__ float sB[FBK][FBN + FPAD];
    const int t = threadIdx.x;
    const int col_blk = blockIdx.x & 15, row_blk = blockIdx.x >> 4;
    const int row0 = row_blk * FBM, col0 = col_blk * FBN;
    const int tx = t & 15, ty = t >> 4;
    float acc[4][4];
    #pragma unroll
    for (int i = 0; i < 4; ++i)
        for (int j = 0; j < 4; ++j) acc[i][j] = 0.f;
    const int ar = t >> 2, ak = (t & 3) * 4, wk = t >> 4, wcc = (t & 15) * 4;
    for (int k0 = 0; k0 < 1024; k0 += FBK) {
        __syncthreads();
        {
            const float4 v = *(const float4*)(hmat + (size_t)(row0 + ar) * 1024 + k0 + ak);
            sA[ak + 0][ar] = v.x; sA[ak + 1][ar] = v.y;
            sA[ak + 2][ar] = v.z; sA[ak + 3][ar] = v.w;
        }
        *(float4*)&sB[wk][wcc] = *(const float4*)(Wy + (size_t)(k0 + wk) * 1024 + col0 + wcc);
        __syncthreads();
        #pragma unroll
        for (int kk = 0; kk < FBK; ++kk) {
            float a[4], bb[4];
            *(float4*)a = *(const float4*)&sA[kk][ty * 4];
            *(float4*)bb = *(const float4*)&sB[kk][tx * 4];
            #pragma unroll
            for (int i = 0; i < 4; ++i)
                for (int j = 0; j < 4; ++j)
                    acc[i][j] += a[i] * bb[j];
        }
    }
    #pragma unroll
    for (int i = 0; i < 4; ++i) {
        const int r = row0 + ty * 4 + i;
        #pragma unroll
        for (int j = 0; j < 4; ++j) {
            const int c = col0 + tx * 4 + j;
            y[(size_t)r * Dd + c] = acc[i][j] + by[c];
        }
    }
}

// ---------------- launch ----------------

extern "C" void kernel_launch(void* const* d_in, const int* in_sizes, int n_in,
                              void* d_out, int out_size, void* d_ws, size_t ws_size,
                              hipStream_t stream) {
    const float* x      = (const float*)d_in[0];
    const float* h_prev = (const float*)d_in[1];
    const float* c_prev = (const float*)d_in[2];
    const float* n_prev = (const float*)d_in[3];
    const float* Wz  = (const float*)d_in[4];
    const float* bWz = (const float*)d_in[5];
    const float* Rz  = (const float*)d_in[6];
    const float* bRz = (const float*)d_in[7];
    const float* bz  = (const float*)d_in[8];
    const float* Wi  = (const float*)d_in[9];
    const float* bWi = (const float*)d_in[10];
    const float* Ri  = (const float*)d_in[11];
    const float* bRi = (const float*)d_in[12];
    const float* bi  = (const float*)d_in[13];
    const float* Wf  = (const float*)d_in[14];
    const float* bWf = (const float*)d_in[15];
    const float* Rf  = (const float*)d_in[16];
    const float* bRf = (const float*)d_in[17];
    const float* bf_ = (const float*)d_in[18];
    const float* Wo  = (const float*)d_in[19];
    const float* bWo = (const float*)d_in[20];
    const float* Ro  = (const float*)d_in[21];
    const float* bRo = (const float*)d_in[22];
    const float* bo  = (const float*)d_in[23];
    const float* Wy  = (const float*)d_in[24];
    const float* by  = (const float*)d_in[25];

    float* y     = (float*)d_out;
    float* out_h = y + (size_t)Bsz * Dd;
    float* out_C = out_h + (size_t)Bsz * Hh;
    float* out_n = out_C + (size_t)Bsz * Hh;

    // ws layout (bytes)
    const size_t OFF_A    = 0;           // 16384*2048*2 = 67108864
    const size_t OFF_WT   = 67108864;    // 4096*2048*2  = 16777216
    const size_t OFF_WYT  = 83886080;    // 1024*1024*2  = 2097152
    const size_t OFF_HBF  = 85983232;    // 16384*1024*2 = 33554432
    const size_t OFF_BS   = 119537664;   // 4*1024*4     = 16384
    const size_t WS_NEED  = 119554048;

    if (ws_size >= WS_NEED) {
        char* ws = (char*)d_ws;
        unsigned short* A_bf = (unsigned short*)(ws + OFF_A);
        unsigned short* WT   = (unsigned short*)(ws + OFF_WT);
        unsigned short* WyT  = (unsigned short*)(ws + OFF_WYT);
        unsigned short* h_bf = (unsigned short*)(ws + OFF_HBF);
        float* bsum          = (float*)(ws + OFF_BS);

        cvt_A<<<16384, 256, 0, stream>>>(x, h_prev, A_bf);
        // gates: g = 0:z 1:i 2:f 3:o ; W -> k [0,1024), R -> k [1024,2048)
        cvt_T<<<256, 256, 0, stream>>>(Wz, WT, 2048, 0,    0, 0);
        cvt_T<<<256, 256, 0, stream>>>(Rz, WT, 2048, 1024, 0, 0);
        cvt_T<<<256, 256, 0, stream>>>(Wi, WT, 2048, 0,    1, 0);
        cvt_T<<<256, 256, 0, stream>>>(Ri, WT, 2048, 1024, 1, 0);
        cvt_T<<<256, 256, 0, stream>>>(Wf, WT, 2048, 0,    2, 0);
        cvt_T<<<256, 256, 0, stream>>>(Rf, WT, 2048, 1024, 2, 0);
        cvt_T<<<256, 256, 0, stream>>>(Wo, WT, 2048, 0,    3, 0);
        cvt_T<<<256, 256, 0, stream>>>(Ro, WT, 2048, 1024, 3, 0);
        cvt_T<<<256, 256, 0, stream>>>(Wy, WyT, 1024, 0,   0, 1);
        bias_sum<<<4, 256, 0, stream>>>(bWz, bRz, bz, bWi, bRi, bi,
                                        bWf, bRf, bf_, bWo, bRo, bo, bsum);

        gemm_gates<<<256, 512, 0, stream>>>(A_bf, WT, bsum, c_prev, n_prev,
                                            out_h, out_C, out_n, h_bf);
        gemm_y<<<256, 512, 0, stream>>>(h_bf, WyT, by, y);
    } else {
        dim3 block(256);
        dim3 grid((Bsz / FBM) * (Hh / FBN));
        fb_gates<<<grid, block, 0, stream>>>(x, h_prev, c_prev, n_prev,
                                             Wz, Rz, Wi, Ri, Wf, Rf, Wo, Ro,
                                             bWz, bRz, bz, bWi, bRi, bi,
                                             bWf, bRf, bf_, bWo, bRo, bo,
                                             out_h, out_C, out_n);
        fb_ygemm<<<grid, block, 0, stream>>>(out_h, Wy, by, y);
    }
}